// Round 15
// baseline (483.006 us; speedup 1.0000x reference)
//
#include <hip/hip_runtime.h>
#include <hip/hip_bf16.h>

#define Bc   2
#define Hc   64
#define Wc   64
#define Lc   4096
#define Cc   96
#define Ec   192
#define Nc   16
#define CATc 768
#define CHUNK 32
#define NCH  128
#define XJ   38

// ---------------- scan-order closed forms (H=W=64) ----------------
__device__ __forceinline__ int inv_d0(int l) {           // bottom-up boustrophedon rows
    int i = l >> 6, j = l & 63;
    int k = 63 - i;
    int m = (k & 1) ? (63 - j) : j;
    return k * 64 + m;
}
__device__ __forceinline__ int inv_d1(int l) {           // left-right boustrophedon cols
    int i = l >> 6, j = l & 63;
    int m = (j & 1) ? (63 - i) : i;
    return j * 64 + m;
}
__device__ __forceinline__ int diag_off(int d) {
    return (d <= 63) ? (d * (d + 1) / 2) : (4096 - (127 - d) * (128 - d) / 2);
}
__device__ __forceinline__ int inv_d2(int l) {           // diagonals
    int i = l >> 6, j = l & 63;
    int d = i + j;
    int st = d > 63 ? d - 63 : 0;
    return diag_off(d) + (i - st);
}
__device__ __forceinline__ int inv_d3(int l) {           // anti-diagonals
    int i = l >> 6, jj = l & 63;
    int j = 63 - jj;
    int d = i + j;
    int st = d > 63 ? d - 63 : 0;
    return diag_off(d) + (i - st);
}

__global__ __launch_bounds__(256) void order_kernel(int* __restrict__ ord) {
    int l = blockIdx.x * 256 + threadIdx.x;
    if (l >= Lc) return;
    ord[0 * Lc + inv_d0(l)] = l;
    ord[1 * Lc + inv_d1(l)] = l;
    ord[2 * Lc + inv_d2(l)] = l;
    ord[3 * Lc + inv_d3(l)] = l;
}

// ---------------- wout [96][192] -> woutT [192][96] ----------------
__global__ __launch_bounds__(256) void wt_kernel(
    const float* __restrict__ wout, float* __restrict__ woutT) {
    int idx = blockIdx.x * 256 + threadIdx.x;      // 72 blocks
    if (idx < Ec * Cc) {
        int k = idx / Cc, o = idx % Cc;
        woutT[idx] = wout[o * Ec + k];             // writes coalesced
    }
}

// ---------------- x [B,L,C] -> xT [B,C,L] (LDS tile transpose) ----------------
__global__ __launch_bounds__(256) void xt_kernel(
    const float* __restrict__ x, float* __restrict__ xT) {
    __shared__ float S[32][97];
    int l0 = blockIdx.x * 32, b = blockIdx.y;
    const float* src = x + ((size_t)b * Lc + l0) * Cc;
    for (int idx = threadIdx.x; idx < 32 * Cc; idx += 256) {
        int l = idx / Cc, c = idx % Cc;
        S[l][c] = src[(size_t)l * Cc + c];          // coalesced along c
    }
    __syncthreads();
    for (int idx = threadIdx.x; idx < 32 * Cc; idx += 256) {
        int c = idx / 32, l = idx % 32;
        xT[((size_t)b * Cc + c) * Lc + l0 + l] = S[l][c];   // coalesced along l
    }
}

// ---------------- directional convs + SiLU -> cat [B,768,L] ----------------
__global__ __launch_bounds__(256) void conv_kernel(
    const float* __restrict__ xT, const float* __restrict__ wh,
    const float* __restrict__ wv, const float* __restrict__ wd1,
    const float* __restrict__ wd2, float* __restrict__ cat) {
    int tile = blockIdx.x, ic = blockIdx.y, b = blockIdx.z;
    int th0 = (tile >> 2) * 16, tw0 = (tile & 3) * 16;
    __shared__ float S[22][24];
    int tid = threadIdx.x;
    const float* xc = xT + ((size_t)b * Cc + ic) * Lc;
    for (int idx = tid; idx < 22 * 22; idx += 256) {
        int r = idx / 22, c = idx % 22;
        int gh = th0 + r - 3, gw = tw0 + c - 3;
        float v = 0.f;
        if (gh >= 0 && gh < 64 && gw >= 0 && gw < 64)
            v = xc[gh * 64 + gw];                   // coalesced along gw
        S[r][c] = v;
    }
    __syncthreads();
    int ti = tid >> 4, tj = tid & 15;
    int pix = (th0 + ti) * 64 + (tw0 + tj);
    for (int s = 0; s < 2; s++) {
        int o = 2 * ic + s;
        float ah = 0.f, av = 0.f, a1 = 0.f, a2 = 0.f;
#pragma unroll
        for (int t = 0; t < 7; t++) {
            ah += S[ti + 3][tj + t] * wh[o * 7 + t];
            av += S[ti + t][tj + 3] * wv[o * 7 + t];
        }
#pragma unroll
        for (int r = 0; r < 7; r++)
#pragma unroll
            for (int c2 = 0; c2 < 7; c2++) {
                float sv = S[ti + r][tj + c2];
                a1 += sv * wd1[o * 49 + r * 7 + c2];
                a2 += sv * wd2[o * 49 + r * 7 + c2];
            }
        cat[((size_t)b * CATc + 0 * Ec + o) * Lc + pix] = ah / (1.f + __expf(-ah));
        cat[((size_t)b * CATc + 1 * Ec + o) * Lc + pix] = av / (1.f + __expf(-av));
        cat[((size_t)b * CATc + 2 * Ec + o) * Lc + pix] = a1 / (1.f + __expf(-a1));
        cat[((size_t)b * CATc + 3 * Ec + o) * Lc + pix] = a2 / (1.f + __expf(-a2));
    }
}

// ---------------- fuse split-K: partials over 8 chunks of 96 channels ----------------
__global__ __launch_bounds__(256) void fuse_part(
    const float* __restrict__ cat, const float* __restrict__ fw,
    float* __restrict__ pxconv) {
    int l = blockIdx.x * 256 + threadIdx.x;
    int o0 = blockIdx.y * 16;
    int cs = blockIdx.z >> 1, b = blockIdx.z & 1;
    int c0 = cs * 96;
    float acc[16];
#pragma unroll
    for (int j = 0; j < 16; j++) acc[j] = 0.f;
#pragma unroll 8
    for (int c = c0; c < c0 + 96; c += 2) {
        float v0 = cat[((size_t)b * CATc + c) * Lc + l];
        float v1 = cat[((size_t)b * CATc + c + 1) * Lc + l];
#pragma unroll
        for (int j = 0; j < 16; j++) {
            acc[j] += v0 * fw[(o0 + j) * CATc + c] + v1 * fw[(o0 + j) * CATc + c + 1];
        }
    }
#pragma unroll
    for (int j = 0; j < 16; j++)
        pxconv[(((size_t)cs * Bc + b) * Cc + o0 + j) * Lc + l] = acc[j];
}

__global__ __launch_bounds__(256) void fuse_reduce(
    const float* __restrict__ pxconv, float* __restrict__ xconv) {
    size_t idx = (size_t)blockIdx.x * 256 + threadIdx.x;   // flat over Bc*Cc*Lc
    const size_t stride = (size_t)Bc * Cc * Lc;
    float s = 0.f;
#pragma unroll
    for (int k = 0; k < 8; k++) s += pxconv[idx + (size_t)k * stride];
    xconv[idx] = s;
}

// ---------------- in_proj: xp/zp [B,L,192] ----------------
__global__ __launch_bounds__(256) void inproj_kernel(
    const float* __restrict__ xconv, const float* __restrict__ w,
    float* __restrict__ xp, float* __restrict__ zp) {
    int l = blockIdx.x * 256 + threadIdx.x;
    int o0 = blockIdx.y * 16;
    int b = blockIdx.z;
    float acc[16];
#pragma unroll
    for (int j = 0; j < 16; j++) acc[j] = 0.f;
#pragma unroll 4
    for (int c = 0; c < Cc; c += 2) {
        float v0 = xconv[((size_t)b * Cc + c) * Lc + l];
        float v1 = xconv[((size_t)b * Cc + c + 1) * Lc + l];
#pragma unroll
        for (int j = 0; j < 16; j++) {
            acc[j] += v0 * w[(o0 + j) * Cc + c] + v1 * w[(o0 + j) * Cc + c + 1];
        }
    }
#pragma unroll
    for (int j = 0; j < 16; j++) {
        int o = o0 + j;
        if (o < Ec) xp[((size_t)b * Lc + l) * Ec + o] = acc[j];
        else        zp[((size_t)b * Lc + l) * Ec + (o - Ec)] = acc[j];
    }
}

// ---------------- xdbl GEMM + fused delta softplus ----------------
__global__ __launch_bounds__(256) void xdbl_kernel(
    const float* __restrict__ xp, const float* __restrict__ xw,
    const float* __restrict__ dtw, const float* __restrict__ dtb,
    float* __restrict__ delta, float* __restrict__ Bst, float* __restrict__ Cst) {
    int rb = blockIdx.x;                 // 256 blocks, 32 rows each
    __shared__ float S[32][193];         // pad 193: conflict-free
    __shared__ float dt6s[32][6];
    const float* src = xp + (size_t)rb * 32 * Ec;
    for (int idx = threadIdx.x; idx < 32 * Ec / 4; idx += 256) {
        int fl = idx * 4;
        int r = fl / Ec, c = fl % Ec;
        float4 v = *(const float4*)(src + fl);
        S[r][c] = v.x; S[r][c + 1] = v.y; S[r][c + 2] = v.z; S[r][c + 3] = v.w;
    }
    __syncthreads();
    for (int t = threadIdx.x; t < 32 * XJ; t += 256) {
        int r = t / XJ, j = t % XJ;
        const float* wrow = xw + j * Ec;
        float s = 0.f;
#pragma unroll 4
        for (int c = 0; c < Ec; c++) s += S[r][c] * wrow[c];
        int row = rb * 32 + r;
        if (j < 6)       dt6s[r][j] = s;
        else if (j < 22) Bst[row * Nc + (j - 6)] = s;
        else             Cst[row * Nc + (j - 22)] = s;
    }
    __syncthreads();
    // delta: softplus(dt6 @ dtw^T + 2*dtb) for 32 rows x 192 e
    for (int idx = threadIdx.x; idx < 32 * Ec; idx += 256) {
        int r = idx / Ec, e = idx % Ec;
        const float* w = dtw + e * 6;
        float s = 2.f * dtb[e];
#pragma unroll
        for (int rr = 0; rr < 6; rr++) s += dt6s[r][rr] * w[rr];
        delta[(size_t)(rb * 32 + r) * Ec + e] = (s > 20.f) ? s : log1pf(__expf(s));
    }
}

// ============ chunked selective scan, thread-owns-e layout ============
// hend layout: [d][b][chunk][n][e]  (chunk stride 3072, n stride 192)
// Pend layout: [b][chunk][n][e]

__global__ __launch_bounds__(192) void scan_part1(
    const float* __restrict__ xp, const int* __restrict__ ord,
    const float* __restrict__ delta, const float* __restrict__ Bst,
    const float* __restrict__ A_log, const float* __restrict__ dirB,
    float* __restrict__ hend, float* __restrict__ Pend) {
    int chunk = blockIdx.x, b = blockIdx.y, d = blockIdx.z;
    int e = threadIdx.x;                 // 0..191
    __shared__ int lord[CHUNK];
    if (threadIdx.x < CHUNK) lord[threadIdx.x] = ord[d * Lc + chunk * CHUNK + threadIdx.x];
    __syncthreads();
    float Aen[Nc], h[Nc], P[Nc], Bd[Nc];
#pragma unroll
    for (int n = 0; n < Nc; n++) {
        Aen[n] = -__expf(A_log[e * Nc + n]);
        Bd[n] = dirB[d * Nc + n];        // block-uniform -> scalar
        h[n] = 0.f; P[n] = 1.f;
    }
    const float* dl  = delta + (size_t)b * Lc * Ec;
    const float* xpb = xp + (size_t)b * Lc * Ec;
    const float* Bb  = Bst + (size_t)b * Lc * Nc;
    int l0 = chunk * CHUNK;
#pragma unroll 2
    for (int t = 0; t < CHUNK; t++) {
        int l = l0 + t;
        float de = dl[(size_t)l * Ec + e];                 // coalesced
        float uu = xpb[(size_t)lord[t] * Ec + e];          // coalesced (uniform row)
        float dub = de * uu;
        const float* Brow = Bb + (size_t)l * Nc;           // uniform -> scalar loads
#pragma unroll
        for (int n = 0; n < Nc; n++) {
            float dA = __expf(de * Aen[n]);
            h[n] = dA * h[n] + dub * (Brow[n] + Bd[n]);
            P[n] *= dA;
        }
    }
    size_t base = ((size_t)(d * Bc + b) * NCH + chunk) * 3072 + e;
#pragma unroll
    for (int n = 0; n < Nc; n++) hend[base + n * Ec] = h[n];
    if (d == 0) {
        size_t pb = ((size_t)b * NCH + chunk) * 3072 + e;
#pragma unroll
        for (int n = 0; n < Nc; n++) Pend[pb + n * Ec] = P[n];
    }
}

__global__ __launch_bounds__(256) void scan_mid(
    float* __restrict__ hend, const float* __restrict__ Pend) {
    int blk = blockIdx.x;            // (d*2+b)*12 + sub
    int sub = blk % 12, db = blk / 12;
    int b = db & 1;
    int pair = sub * 256 + threadIdx.x;   // 0..3071 = (n,e) flat
    size_t base  = (size_t)db * NCH * 3072 + pair;
    size_t pbase = (size_t)b * NCH * 3072 + pair;
    float h = 0.f;
    for (int c = 0; c < NCH; c++) {
        float hc = hend[base + (size_t)c * 3072];
        float P  = Pend[pbase + (size_t)c * 3072];
        hend[base + (size_t)c * 3072] = h;   // h_in for chunk c
        h = P * h + hc;
    }
}

__global__ __launch_bounds__(192) void scan_part2(
    const float* __restrict__ xp, const int* __restrict__ ord,
    const float* __restrict__ delta, const float* __restrict__ Bst,
    const float* __restrict__ Cst, const float* __restrict__ A_log,
    const float* __restrict__ Dp, const float* __restrict__ dirB,
    const float* __restrict__ hend, float* __restrict__ ydir) {
    int chunk = blockIdx.x, b = blockIdx.y, d = blockIdx.z;
    int e = threadIdx.x;                 // 0..191
    __shared__ int lord[CHUNK];
    if (threadIdx.x < CHUNK) lord[threadIdx.x] = ord[d * Lc + chunk * CHUNK + threadIdx.x];
    __syncthreads();
    float Aen[Nc], h[Nc], Bd[Nc];
    size_t base = ((size_t)(d * Bc + b) * NCH + chunk) * 3072 + e;
#pragma unroll
    for (int n = 0; n < Nc; n++) {
        Aen[n] = -__expf(A_log[e * Nc + n]);
        Bd[n] = dirB[d * Nc + n];
        h[n] = hend[base + n * Ec];
    }
    float De = Dp[e];
    const float* dl  = delta + (size_t)b * Lc * Ec;
    const float* xpb = xp + (size_t)b * Lc * Ec;
    const float* Bb  = Bst + (size_t)b * Lc * Nc;
    const float* Cb  = Cst + (size_t)b * Lc * Nc;
    float* yo = ydir + ((size_t)(d * Bc + b) * Lc) * Ec + e;
    int l0 = chunk * CHUNK;
#pragma unroll 2
    for (int t = 0; t < CHUNK; t++) {
        int l = l0 + t;
        float de = dl[(size_t)l * Ec + e];
        float uu = xpb[(size_t)lord[t] * Ec + e];
        float dub = de * uu;
        const float* Brow = Bb + (size_t)l * Nc;
        const float* Crow = Cb + (size_t)l * Nc;
        float acc = De * uu;
#pragma unroll
        for (int n = 0; n < Nc; n++) {
            float dA = __expf(de * Aen[n]);
            h[n] = dA * h[n] + dub * (Brow[n] + Bd[n]);
            acc += h[n] * Crow[n];
        }
        yo[(size_t)l * Ec] = acc;                           // coalesced
    }
}

// ---------------- local cluster: one block per 8x8 tile ----------------
__global__ __launch_bounds__(64) void cluster_kernel(
    const float* __restrict__ xconv,
    const float* __restrict__ fwp, const float* __restrict__ fbp,
    const float* __restrict__ vwp, const float* __restrict__ vbp,
    const float* __restrict__ pwp, const float* __restrict__ pbp,
    const float* __restrict__ alphap, const float* __restrict__ betap,
    float* __restrict__ c96) {
    int g = blockIdx.x;
    int b = g >> 6, Wg = (g >> 3) & 7, Hg = g & 7;
    int p = threadIdx.x;
    int wi = p >> 3, hj = p & 7;
    int lsp = (Wg * 8 + wi) * 64 + (Hg * 8 + hj);
    __shared__ float fS[64][6], vS[64][6];
    __shared__ float cen[25][6], vc[25][6], cnorm[25];
    __shared__ float simb[64];
    __shared__ int kb[64];
    __shared__ float agg[25][6];
    float fr[6], vr[6];
#pragma unroll
    for (int oc = 0; oc < 6; oc++) { fr[oc] = fbp[oc]; vr[oc] = vbp[oc]; }
    for (int c = 0; c < 48; c++) {
        float v1 = xconv[((size_t)b * Cc + c) * Lc + lsp];
        float v2 = xconv[((size_t)b * Cc + 48 + c) * Lc + lsp];
#pragma unroll
        for (int oc = 0; oc < 6; oc++) {
            fr[oc] += v1 * fwp[oc * 48 + c];
            vr[oc] += v2 * vwp[oc * 48 + c];
        }
    }
#pragma unroll
    for (int oc = 0; oc < 6; oc++) { fS[p][oc] = fr[oc]; vS[p][oc] = vr[oc]; }
    __syncthreads();
    // adaptive-pool bins for 8->5
    const int bs[5] = {0, 1, 3, 4, 6}, be[5] = {2, 4, 5, 7, 8};
    for (int t = p; t < 150; t += 64) {
        int k = t / 6, oc = t % 6;
        int ki = k / 5, kj = k % 5;
        float sf = 0.f, sv = 0.f;
        int cnt = 0;
        for (int ii = bs[ki]; ii < be[ki]; ii++)
            for (int jj = bs[kj]; jj < be[kj]; jj++) {
                sf += fS[ii * 8 + jj][oc];
                sv += vS[ii * 8 + jj][oc];
                cnt++;
            }
        cen[k][oc] = sf / cnt;
        vc[k][oc] = sv / cnt;
    }
    __syncthreads();
    if (p < 25) {
        float s = 0.f;
#pragma unroll
        for (int oc = 0; oc < 6; oc++) s += cen[p][oc] * cen[p][oc];
        cnorm[p] = 1.f / fmaxf(sqrtf(s), 1e-12f);
    }
    __syncthreads();
    float fn2 = 0.f;
#pragma unroll
    for (int oc = 0; oc < 6; oc++) fn2 += fr[oc] * fr[oc];
    float finv = 1.f / fmaxf(sqrtf(fn2), 1e-12f);
    float alpha = alphap[0], beta = betap[0];
    float best = -1.f;
    int bestk = 0;
    for (int k = 0; k < 25; k++) {
        float dot = 0.f;
#pragma unroll
        for (int oc = 0; oc < 6; oc++) dot += cen[k][oc] * fr[oc];
        float xv = beta + alpha * dot * cnorm[k] * finv;
        float s = 1.f / (1.f + __expf(-xv));
        if (s > best) { best = s; bestk = k; }   // first-occurrence argmax
    }
    simb[p] = best;
    kb[p] = bestk;
    __syncthreads();
    if (p < 25) {
        float sum_s = 0.f;
        float av[6];
#pragma unroll
        for (int oc = 0; oc < 6; oc++) av[oc] = vc[p][oc];
        for (int q = 0; q < 64; q++) {
            if (kb[q] == p) {
                float s = simb[q];
                sum_s += s;
#pragma unroll
                for (int oc = 0; oc < 6; oc++) av[oc] += s * vS[q][oc];
            }
        }
        float invd = 1.f / (sum_s + 1.f);
#pragma unroll
        for (int oc = 0; oc < 6; oc++) agg[p][oc] = av[oc] * invd;
    }
    __syncthreads();
    float outp[6];
#pragma unroll
    for (int oc = 0; oc < 6; oc++) outp[oc] = agg[kb[p]][oc] * simb[p];
    float* orow = c96 + ((size_t)b * Lc + lsp) * Cc;
    for (int oo = 0; oo < Cc; oo++) {
        float s = pbp[oo];
#pragma unroll
        for (int oc = 0; oc < 6; oc++) s += outp[oc] * pwp[oo * 6 + oc];
        orow[oo] = s;
    }
}

// ---------------- cluster projection 96 -> 192 ----------------
__global__ __launch_bounds__(256) void clproj_kernel(
    const float* __restrict__ c96, const float* __restrict__ w,
    const float* __restrict__ bias, float* __restrict__ cl) {
    int l = blockIdx.x * 256 + threadIdx.x;
    int o0 = blockIdx.y * 16;
    int b = blockIdx.z;
    const float* row = c96 + ((size_t)b * Lc + l) * Cc;
    float acc[16];
#pragma unroll
    for (int j = 0; j < 16; j++) acc[j] = bias[o0 + j];
#pragma unroll 4
    for (int c = 0; c < Cc; c += 2) {
        float v0 = row[c], v1 = row[c + 1];
#pragma unroll
        for (int j = 0; j < 16; j++) {
            acc[j] += v0 * w[(o0 + j) * Cc + c] + v1 * w[(o0 + j) * Cc + c + 1];
        }
    }
#pragma unroll
    for (int j = 0; j < 16; j++)
        cl[((size_t)b * Lc + l) * Ec + o0 + j] = acc[j];
}

// ---------------- gather y dirs + 3x LayerNorm + branch softmax + out_proj ----------------
__global__ __launch_bounds__(256) void final_kernel(
    const float* __restrict__ ydir, const float* __restrict__ zp,
    const float* __restrict__ cl, const float* __restrict__ bc,
    const float* __restrict__ lnw, const float* __restrict__ lnb,
    const float* __restrict__ woutT, float* __restrict__ out) {
    __shared__ float comb[4][Ec];
    int wave = threadIdx.x >> 6, lane = threadIdx.x & 63;
    int row = blockIdx.x * 4 + wave;
    int b = row >> 12, lp = row & (Lc - 1);
    int iv0 = inv_d0(lp), iv1 = inv_d1(lp), iv2 = inv_d2(lp), iv3 = inv_d3(lp);
    const float* y0 = ydir + ((size_t)(0 * Bc + b) * Lc + iv0) * Ec;
    const float* y1 = ydir + ((size_t)(1 * Bc + b) * Lc + iv1) * Ec;
    const float* y2 = ydir + ((size_t)(2 * Bc + b) * Lc + iv2) * Ec;
    const float* y3 = ydir + ((size_t)(3 * Bc + b) * Lc + iv3) * Ec;
    const float* zr = zp + ((size_t)b * Lc + lp) * Ec;
    const float* cr = cl + ((size_t)b * Lc + lp) * Ec;
    float ys[3], zv[3], cv[3];
    float s1 = 0, s2 = 0, z1 = 0, z2 = 0, c1 = 0, c2 = 0;
#pragma unroll
    for (int t = 0; t < 3; t++) {
        int i = lane + t * 64;
        float v = y0[i] + y1[i] + y2[i] + y3[i];
        ys[t] = v; s1 += v; s2 += v * v;
        float z = zr[i]; zv[t] = z; z1 += z; z2 += z * z;
        float c = cr[i]; cv[t] = c; c1 += c; c2 += c * c;
    }
#pragma unroll
    for (int o = 32; o >= 1; o >>= 1) {
        s1 += __shfl_xor(s1, o, 64); s2 += __shfl_xor(s2, o, 64);
        z1 += __shfl_xor(z1, o, 64); z2 += __shfl_xor(z2, o, 64);
        c1 += __shfl_xor(c1, o, 64); c2 += __shfl_xor(c2, o, 64);
    }
    const float invE = 1.f / (float)Ec;
    float ym = s1 * invE, yvr = rsqrtf(s2 * invE - ym * ym + 1e-5f);
    float zm = z1 * invE, zvr = rsqrtf(z2 * invE - zm * zm + 1e-5f);
    float cm = c1 * invE, cvr = rsqrtf(c2 * invE - cm * cm + 1e-5f);
#pragma unroll
    for (int t = 0; t < 3; t++) {
        int i = lane + t * 64;
        float g = lnw[i], bb = lnb[i];
        float a0 = (ys[t] - ym) * yvr * g + bb;
        float a1 = (zv[t] - zm) * zvr * g + bb;
        float a2 = (cv[t] - cm) * cvr * g + bb;
        float w0 = bc[i], w1 = bc[Ec + i], w2 = bc[2 * Ec + i];
        float mx = fmaxf(w0, fmaxf(w1, w2));
        float e0 = __expf(w0 - mx), e1 = __expf(w1 - mx), e2 = __expf(w2 - mx);
        float inv = 1.f / (e0 + e1 + e2);
        comb[wave][i] = (e0 * a0 + e1 * a1 + e2 * a2) * inv;
    }
    __syncthreads();
    // out_proj: lane = o; woutT[k][o] coalesced; comb[wave][k] LDS broadcast.
    float r0 = 0.f, r1 = 0.f;
#pragma unroll 4
    for (int k = 0; k < Ec; k++) {
        float cvk = comb[wave][k];
        float w0 = woutT[k * Cc + lane];
        float w1 = woutT[k * Cc + 64 + lane];
        r0 += cvk * w0;
        r1 += cvk * w1;
    }
    float* orow = out + (size_t)row * Cc;
    orow[lane] = r0;                      // o = 0..63, coalesced
    if (lane < 32) orow[64 + lane] = r1;  // o = 64..95, coalesced
}

extern "C" void kernel_launch(void* const* d_in, const int* in_sizes, int n_in,
                              void* d_out, int out_size, void* d_ws, size_t ws_size,
                              hipStream_t stream) {
    const float* x       = (const float*)d_in[0];
    const float* wh      = (const float*)d_in[3];
    const float* wv      = (const float*)d_in[4];
    const float* wd1     = (const float*)d_in[5];
    const float* wd2     = (const float*)d_in[6];
    const float* fw      = (const float*)d_in[7];
    const float* ipw     = (const float*)d_in[8];
    const float* xw      = (const float*)d_in[9];
    const float* dtw     = (const float*)d_in[10];
    const float* dtb     = (const float*)d_in[11];
    const float* A_log   = (const float*)d_in[12];
    const float* Dp      = (const float*)d_in[13];
    const float* dirB    = (const float*)d_in[14];
    const float* wout    = (const float*)d_in[15];
    const float* alphap  = (const float*)d_in[16];
    const float* betap   = (const float*)d_in[17];
    const float* fwp     = (const float*)d_in[18];
    const float* fbp     = (const float*)d_in[19];
    const float* vwp     = (const float*)d_in[20];
    const float* vbp     = (const float*)d_in[21];
    const float* pwp     = (const float*)d_in[22];
    const float* pbp     = (const float*)d_in[23];
    const float* clw     = (const float*)d_in[24];
    const float* clb     = (const float*)d_in[25];
    const float* bc      = (const float*)d_in[26];
    const float* lnw     = (const float*)d_in[27];
    const float* lnb     = (const float*)d_in[28];
    float* out = (float*)d_out;

    float* wsf = (float*)d_ws;
    size_t off = 0;
    int* ord      = (int*)wsf;             off += 4 * Lc;                 // 64 KB
    float* cat    = wsf + off;             off += (size_t)Bc * CATc * Lc; // 24 MB (reused as ydir)
    float* xconv  = wsf + off;             off += (size_t)Bc * Cc * Lc;   // 3 MB
    float* xp     = wsf + off;             off += (size_t)Bc * Lc * Ec;   // 6 MB (reused as c96)
    float* zpb    = wsf + off;             off += (size_t)Bc * Lc * Ec;   // 6 MB
    float* deltab = wsf + off;             off += (size_t)Bc * Lc * Ec;   // 6 MB (reused as cl)
    float* Bst    = wsf + off;             off += (size_t)Bc * Lc * Nc;   // 0.5 MB
    float* Cst    = wsf + off;             off += (size_t)Bc * Lc * Nc;   // 0.5 MB
    float* hend   = wsf + off;             off += (size_t)4 * Bc * NCH * Ec * Nc; // 12.6 MB
    float* Pend   = wsf + off;             off += (size_t)Bc * NCH * Ec * Nc;     // 3.1 MB
    float* woutT  = wsf + off;             off += (size_t)Ec * Cc + 64;           // 74 KB (+64 pad)
    // total ≈ 64.3 MB
    float* ydir = cat;     // cat dead after fuse; same size as ydir
    float* c96  = xp;      // xp dead after scan_part2 (stream-serialized)
    float* cl   = deltab;  // delta dead after scan_part2
    // fuse 8-way split-K partials: 8*Bc*Cc*Lc = 6,291,456 floats — spans
    // xp..hend-prefix (xp/zpb/delta/Bst/Cst written only after fuse_reduce;
    // xT in hend prefix dead after conv; all stream-serialized)
    float* pxconv = xp;
    // xT (0.79M floats) aliases hend: dead until scan_part1, conv runs first
    float* xT = hend;

    order_kernel<<<16, 256, 0, stream>>>(ord);
    wt_kernel<<<72, 256, 0, stream>>>(wout, woutT);
    xt_kernel<<<dim3(128, 2), 256, 0, stream>>>(x, xT);
    conv_kernel<<<dim3(16, 96, 2), 256, 0, stream>>>(xT, wh, wv, wd1, wd2, cat);
    fuse_part<<<dim3(16, 6, 16), 256, 0, stream>>>(cat, fw, pxconv);
    fuse_reduce<<<3072, 256, 0, stream>>>(pxconv, xconv);
    inproj_kernel<<<dim3(16, 24, 2), 256, 0, stream>>>(xconv, ipw, xp, zpb);
    xdbl_kernel<<<256, 256, 0, stream>>>(xp, xw, dtw, dtb, deltab, Bst, Cst);
    scan_part1<<<dim3(NCH, 2, 4), 192, 0, stream>>>(xp, ord, deltab, Bst,
                                                    A_log, dirB, hend, Pend);
    scan_mid<<<96, 256, 0, stream>>>(hend, Pend);
    scan_part2<<<dim3(NCH, 2, 4), 192, 0, stream>>>(xp, ord, deltab, Bst, Cst,
                                                    A_log, Dp, dirB, hend, ydir);
    cluster_kernel<<<128, 64, 0, stream>>>(xconv, fwp, fbp, vwp, vbp, pwp, pbp,
                                           alphap, betap, c96);
    clproj_kernel<<<dim3(16, 12, 2), 256, 0, stream>>>(c96, clw, clb, cl);
    final_kernel<<<2048, 256, 0, stream>>>(ydir, zpb, cl, bc, lnw, lnb, woutT, out);
}

// Round 16
// 442.268 us; speedup vs baseline: 1.0921x; 1.0921x over previous
//
#include <hip/hip_runtime.h>
#include <hip/hip_bf16.h>

#define Bc   2
#define Hc   64
#define Wc   64
#define Lc   4096
#define Cc   96
#define Ec   192
#define Nc   16
#define CATc 768
#define CHUNK 32
#define NCH  128
#define XJ   38

// ---------------- scan-order closed forms (H=W=64) ----------------
__device__ __forceinline__ int inv_d0(int l) {           // bottom-up boustrophedon rows
    int i = l >> 6, j = l & 63;
    int k = 63 - i;
    int m = (k & 1) ? (63 - j) : j;
    return k * 64 + m;
}
__device__ __forceinline__ int inv_d1(int l) {           // left-right boustrophedon cols
    int i = l >> 6, j = l & 63;
    int m = (j & 1) ? (63 - i) : i;
    return j * 64 + m;
}
__device__ __forceinline__ int diag_off(int d) {
    return (d <= 63) ? (d * (d + 1) / 2) : (4096 - (127 - d) * (128 - d) / 2);
}
__device__ __forceinline__ int inv_d2(int l) {           // diagonals
    int i = l >> 6, j = l & 63;
    int d = i + j;
    int st = d > 63 ? d - 63 : 0;
    return diag_off(d) + (i - st);
}
__device__ __forceinline__ int inv_d3(int l) {           // anti-diagonals
    int i = l >> 6, jj = l & 63;
    int j = 63 - jj;
    int d = i + j;
    int st = d > 63 ? d - 63 : 0;
    return diag_off(d) + (i - st);
}

__global__ __launch_bounds__(256) void order_kernel(int* __restrict__ ord) {
    int l = blockIdx.x * 256 + threadIdx.x;
    if (l >= Lc) return;
    ord[0 * Lc + inv_d0(l)] = l;
    ord[1 * Lc + inv_d1(l)] = l;
    ord[2 * Lc + inv_d2(l)] = l;
    ord[3 * Lc + inv_d3(l)] = l;
}

// ---------------- wout [96][192] -> woutT [192][96] ----------------
__global__ __launch_bounds__(256) void wt_kernel(
    const float* __restrict__ wout, float* __restrict__ woutT) {
    int idx = blockIdx.x * 256 + threadIdx.x;      // 72 blocks
    if (idx < Ec * Cc) {
        int k = idx / Cc, o = idx % Cc;
        woutT[idx] = wout[o * Ec + k];             // writes coalesced
    }
}

// ---------------- x [B,L,C] -> xT [B,C,L] (LDS tile transpose) ----------------
__global__ __launch_bounds__(256) void xt_kernel(
    const float* __restrict__ x, float* __restrict__ xT) {
    __shared__ float S[32][97];
    int l0 = blockIdx.x * 32, b = blockIdx.y;
    const float* src = x + ((size_t)b * Lc + l0) * Cc;
    for (int idx = threadIdx.x; idx < 32 * Cc; idx += 256) {
        int l = idx / Cc, c = idx % Cc;
        S[l][c] = src[(size_t)l * Cc + c];          // coalesced along c
    }
    __syncthreads();
    for (int idx = threadIdx.x; idx < 32 * Cc; idx += 256) {
        int c = idx / 32, l = idx % 32;
        xT[((size_t)b * Cc + c) * Lc + l0 + l] = S[l][c];   // coalesced along l
    }
}

// ---------------- directional convs + SiLU -> cat [B,768,L] ----------------
__global__ __launch_bounds__(256) void conv_kernel(
    const float* __restrict__ xT, const float* __restrict__ wh,
    const float* __restrict__ wv, const float* __restrict__ wd1,
    const float* __restrict__ wd2, float* __restrict__ cat) {
    int tile = blockIdx.x, ic = blockIdx.y, b = blockIdx.z;
    int th0 = (tile >> 2) * 16, tw0 = (tile & 3) * 16;
    __shared__ float S[22][24];
    int tid = threadIdx.x;
    const float* xc = xT + ((size_t)b * Cc + ic) * Lc;
    for (int idx = tid; idx < 22 * 22; idx += 256) {
        int r = idx / 22, c = idx % 22;
        int gh = th0 + r - 3, gw = tw0 + c - 3;
        float v = 0.f;
        if (gh >= 0 && gh < 64 && gw >= 0 && gw < 64)
            v = xc[gh * 64 + gw];                   // coalesced along gw
        S[r][c] = v;
    }
    __syncthreads();
    int ti = tid >> 4, tj = tid & 15;
    int pix = (th0 + ti) * 64 + (tw0 + tj);
    for (int s = 0; s < 2; s++) {
        int o = 2 * ic + s;
        float ah = 0.f, av = 0.f, a1 = 0.f, a2 = 0.f;
#pragma unroll
        for (int t = 0; t < 7; t++) {
            ah += S[ti + 3][tj + t] * wh[o * 7 + t];
            av += S[ti + t][tj + 3] * wv[o * 7 + t];
        }
#pragma unroll
        for (int r = 0; r < 7; r++)
#pragma unroll
            for (int c2 = 0; c2 < 7; c2++) {
                float sv = S[ti + r][tj + c2];
                a1 += sv * wd1[o * 49 + r * 7 + c2];
                a2 += sv * wd2[o * 49 + r * 7 + c2];
            }
        cat[((size_t)b * CATc + 0 * Ec + o) * Lc + pix] = ah / (1.f + __expf(-ah));
        cat[((size_t)b * CATc + 1 * Ec + o) * Lc + pix] = av / (1.f + __expf(-av));
        cat[((size_t)b * CATc + 2 * Ec + o) * Lc + pix] = a1 / (1.f + __expf(-a1));
        cat[((size_t)b * CATc + 3 * Ec + o) * Lc + pix] = a2 / (1.f + __expf(-a2));
    }
}

// ---------------- fuse split-K: partials over 8 chunks of 96 channels ----------------
// unroll 4 is the verified knee (r13/r14); 8 explodes VALU (r15), 0 stalls (r12)
__global__ __launch_bounds__(256) void fuse_part(
    const float* __restrict__ cat, const float* __restrict__ fw,
    float* __restrict__ pxconv) {
    int l = blockIdx.x * 256 + threadIdx.x;
    int o0 = blockIdx.y * 16;
    int cs = blockIdx.z >> 1, b = blockIdx.z & 1;
    int c0 = cs * 96;
    float acc[16];
#pragma unroll
    for (int j = 0; j < 16; j++) acc[j] = 0.f;
#pragma unroll 4
    for (int c = c0; c < c0 + 96; c += 2) {
        float v0 = cat[((size_t)b * CATc + c) * Lc + l];
        float v1 = cat[((size_t)b * CATc + c + 1) * Lc + l];
#pragma unroll
        for (int j = 0; j < 16; j++) {
            acc[j] += v0 * fw[(o0 + j) * CATc + c] + v1 * fw[(o0 + j) * CATc + c + 1];
        }
    }
#pragma unroll
    for (int j = 0; j < 16; j++)
        pxconv[(((size_t)cs * Bc + b) * Cc + o0 + j) * Lc + l] = acc[j];
}

__global__ __launch_bounds__(256) void fuse_reduce(
    const float* __restrict__ pxconv, float* __restrict__ xconv) {
    size_t idx = (size_t)blockIdx.x * 256 + threadIdx.x;   // flat over Bc*Cc*Lc
    const size_t stride = (size_t)Bc * Cc * Lc;
    float s = 0.f;
#pragma unroll
    for (int k = 0; k < 8; k++) s += pxconv[idx + (size_t)k * stride];
    xconv[idx] = s;
}

// ---------------- in_proj: xp/zp [B,L,192] ----------------
__global__ __launch_bounds__(256) void inproj_kernel(
    const float* __restrict__ xconv, const float* __restrict__ w,
    float* __restrict__ xp, float* __restrict__ zp) {
    int l = blockIdx.x * 256 + threadIdx.x;
    int o0 = blockIdx.y * 16;
    int b = blockIdx.z;
    float acc[16];
#pragma unroll
    for (int j = 0; j < 16; j++) acc[j] = 0.f;
#pragma unroll 4
    for (int c = 0; c < Cc; c += 2) {
        float v0 = xconv[((size_t)b * Cc + c) * Lc + l];
        float v1 = xconv[((size_t)b * Cc + c + 1) * Lc + l];
#pragma unroll
        for (int j = 0; j < 16; j++) {
            acc[j] += v0 * w[(o0 + j) * Cc + c] + v1 * w[(o0 + j) * Cc + c + 1];
        }
    }
#pragma unroll
    for (int j = 0; j < 16; j++) {
        int o = o0 + j;
        if (o < Ec) xp[((size_t)b * Lc + l) * Ec + o] = acc[j];
        else        zp[((size_t)b * Lc + l) * Ec + (o - Ec)] = acc[j];
    }
}

// ---------------- xdbl GEMM + fused delta softplus ----------------
__global__ __launch_bounds__(256) void xdbl_kernel(
    const float* __restrict__ xp, const float* __restrict__ xw,
    const float* __restrict__ dtw, const float* __restrict__ dtb,
    float* __restrict__ delta, float* __restrict__ Bst, float* __restrict__ Cst) {
    int rb = blockIdx.x;                 // 256 blocks, 32 rows each
    __shared__ float S[32][193];         // pad 193: conflict-free
    __shared__ float dt6s[32][6];
    const float* src = xp + (size_t)rb * 32 * Ec;
    for (int idx = threadIdx.x; idx < 32 * Ec / 4; idx += 256) {
        int fl = idx * 4;
        int r = fl / Ec, c = fl % Ec;
        float4 v = *(const float4*)(src + fl);
        S[r][c] = v.x; S[r][c + 1] = v.y; S[r][c + 2] = v.z; S[r][c + 3] = v.w;
    }
    __syncthreads();
    for (int t = threadIdx.x; t < 32 * XJ; t += 256) {
        int r = t / XJ, j = t % XJ;
        const float* wrow = xw + j * Ec;
        float s = 0.f;
#pragma unroll 4
        for (int c = 0; c < Ec; c++) s += S[r][c] * wrow[c];
        int row = rb * 32 + r;
        if (j < 6)       dt6s[r][j] = s;
        else if (j < 22) Bst[row * Nc + (j - 6)] = s;
        else             Cst[row * Nc + (j - 22)] = s;
    }
    __syncthreads();
    // delta: softplus(dt6 @ dtw^T + 2*dtb) for 32 rows x 192 e
    for (int idx = threadIdx.x; idx < 32 * Ec; idx += 256) {
        int r = idx / Ec, e = idx % Ec;
        const float* w = dtw + e * 6;
        float s = 2.f * dtb[e];
#pragma unroll
        for (int rr = 0; rr < 6; rr++) s += dt6s[r][rr] * w[rr];
        delta[(size_t)(rb * 32 + r) * Ec + e] = (s > 20.f) ? s : log1pf(__expf(s));
    }
}

// ============ chunked selective scan, thread-owns-e layout ============
// hend layout: [d][b][chunk][n][e]  (chunk stride 3072, n stride 192)
// Pend layout: [b][chunk][n][e]

__global__ __launch_bounds__(192) void scan_part1(
    const float* __restrict__ xp, const int* __restrict__ ord,
    const float* __restrict__ delta, const float* __restrict__ Bst,
    const float* __restrict__ A_log, const float* __restrict__ dirB,
    float* __restrict__ hend, float* __restrict__ Pend) {
    int chunk = blockIdx.x, b = blockIdx.y, d = blockIdx.z;
    int e = threadIdx.x;                 // 0..191
    __shared__ int lord[CHUNK];
    if (threadIdx.x < CHUNK) lord[threadIdx.x] = ord[d * Lc + chunk * CHUNK + threadIdx.x];
    __syncthreads();
    float Aen[Nc], h[Nc], P[Nc], Bd[Nc];
#pragma unroll
    for (int n = 0; n < Nc; n++) {
        Aen[n] = -__expf(A_log[e * Nc + n]);
        Bd[n] = dirB[d * Nc + n];        // block-uniform -> scalar
        h[n] = 0.f; P[n] = 1.f;
    }
    const float* dl  = delta + (size_t)b * Lc * Ec;
    const float* xpb = xp + (size_t)b * Lc * Ec;
    const float* Bb  = Bst + (size_t)b * Lc * Nc;
    int l0 = chunk * CHUNK;
#pragma unroll 2
    for (int t = 0; t < CHUNK; t++) {
        int l = l0 + t;
        float de = dl[(size_t)l * Ec + e];                 // coalesced
        float uu = xpb[(size_t)lord[t] * Ec + e];          // coalesced (uniform row)
        float dub = de * uu;
        const float* Brow = Bb + (size_t)l * Nc;           // uniform -> scalar loads
#pragma unroll
        for (int n = 0; n < Nc; n++) {
            float dA = __expf(de * Aen[n]);
            h[n] = dA * h[n] + dub * (Brow[n] + Bd[n]);
            P[n] *= dA;
        }
    }
    size_t base = ((size_t)(d * Bc + b) * NCH + chunk) * 3072 + e;
#pragma unroll
    for (int n = 0; n < Nc; n++) hend[base + n * Ec] = h[n];
    if (d == 0) {
        size_t pb = ((size_t)b * NCH + chunk) * 3072 + e;
#pragma unroll
        for (int n = 0; n < Nc; n++) Pend[pb + n * Ec] = P[n];
    }
}

__global__ __launch_bounds__(256) void scan_mid(
    float* __restrict__ hend, const float* __restrict__ Pend) {
    int blk = blockIdx.x;            // (d*2+b)*12 + sub
    int sub = blk % 12, db = blk / 12;
    int b = db & 1;
    int pair = sub * 256 + threadIdx.x;   // 0..3071 = (n,e) flat
    size_t base  = (size_t)db * NCH * 3072 + pair;
    size_t pbase = (size_t)b * NCH * 3072 + pair;
    float h = 0.f;
    for (int c = 0; c < NCH; c++) {
        float hc = hend[base + (size_t)c * 3072];
        float P  = Pend[pbase + (size_t)c * 3072];
        hend[base + (size_t)c * 3072] = h;   // h_in for chunk c
        h = P * h + hc;
    }
}

__global__ __launch_bounds__(192) void scan_part2(
    const float* __restrict__ xp, const int* __restrict__ ord,
    const float* __restrict__ delta, const float* __restrict__ Bst,
    const float* __restrict__ Cst, const float* __restrict__ A_log,
    const float* __restrict__ Dp, const float* __restrict__ dirB,
    const float* __restrict__ hend, float* __restrict__ ydir) {
    int chunk = blockIdx.x, b = blockIdx.y, d = blockIdx.z;
    int e = threadIdx.x;                 // 0..191
    __shared__ int lord[CHUNK];
    if (threadIdx.x < CHUNK) lord[threadIdx.x] = ord[d * Lc + chunk * CHUNK + threadIdx.x];
    __syncthreads();
    float Aen[Nc], h[Nc], Bd[Nc];
    size_t base = ((size_t)(d * Bc + b) * NCH + chunk) * 3072 + e;
#pragma unroll
    for (int n = 0; n < Nc; n++) {
        Aen[n] = -__expf(A_log[e * Nc + n]);
        Bd[n] = dirB[d * Nc + n];
        h[n] = hend[base + n * Ec];
    }
    float De = Dp[e];
    const float* dl  = delta + (size_t)b * Lc * Ec;
    const float* xpb = xp + (size_t)b * Lc * Ec;
    const float* Bb  = Bst + (size_t)b * Lc * Nc;
    const float* Cb  = Cst + (size_t)b * Lc * Nc;
    float* yo = ydir + ((size_t)(d * Bc + b) * Lc) * Ec + e;
    int l0 = chunk * CHUNK;
#pragma unroll 2
    for (int t = 0; t < CHUNK; t++) {
        int l = l0 + t;
        float de = dl[(size_t)l * Ec + e];
        float uu = xpb[(size_t)lord[t] * Ec + e];
        float dub = de * uu;
        const float* Brow = Bb + (size_t)l * Nc;
        const float* Crow = Cb + (size_t)l * Nc;
        float acc = De * uu;
#pragma unroll
        for (int n = 0; n < Nc; n++) {
            float dA = __expf(de * Aen[n]);
            h[n] = dA * h[n] + dub * (Brow[n] + Bd[n]);
            acc += h[n] * Crow[n];
        }
        yo[(size_t)l * Ec] = acc;                           // coalesced
    }
}

// ---------------- local cluster: one block per 8x8 tile ----------------
__global__ __launch_bounds__(64) void cluster_kernel(
    const float* __restrict__ xconv,
    const float* __restrict__ fwp, const float* __restrict__ fbp,
    const float* __restrict__ vwp, const float* __restrict__ vbp,
    const float* __restrict__ pwp, const float* __restrict__ pbp,
    const float* __restrict__ alphap, const float* __restrict__ betap,
    float* __restrict__ c96) {
    int g = blockIdx.x;
    int b = g >> 6, Wg = (g >> 3) & 7, Hg = g & 7;
    int p = threadIdx.x;
    int wi = p >> 3, hj = p & 7;
    int lsp = (Wg * 8 + wi) * 64 + (Hg * 8 + hj);
    __shared__ float fS[64][6], vS[64][6];
    __shared__ float cen[25][6], vc[25][6], cnorm[25];
    __shared__ float simb[64];
    __shared__ int kb[64];
    __shared__ float agg[25][6];
    float fr[6], vr[6];
#pragma unroll
    for (int oc = 0; oc < 6; oc++) { fr[oc] = fbp[oc]; vr[oc] = vbp[oc]; }
    for (int c = 0; c < 48; c++) {
        float v1 = xconv[((size_t)b * Cc + c) * Lc + lsp];
        float v2 = xconv[((size_t)b * Cc + 48 + c) * Lc + lsp];
#pragma unroll
        for (int oc = 0; oc < 6; oc++) {
            fr[oc] += v1 * fwp[oc * 48 + c];
            vr[oc] += v2 * vwp[oc * 48 + c];
        }
    }
#pragma unroll
    for (int oc = 0; oc < 6; oc++) { fS[p][oc] = fr[oc]; vS[p][oc] = vr[oc]; }
    __syncthreads();
    // adaptive-pool bins for 8->5
    const int bs[5] = {0, 1, 3, 4, 6}, be[5] = {2, 4, 5, 7, 8};
    for (int t = p; t < 150; t += 64) {
        int k = t / 6, oc = t % 6;
        int ki = k / 5, kj = k % 5;
        float sf = 0.f, sv = 0.f;
        int cnt = 0;
        for (int ii = bs[ki]; ii < be[ki]; ii++)
            for (int jj = bs[kj]; jj < be[kj]; jj++) {
                sf += fS[ii * 8 + jj][oc];
                sv += vS[ii * 8 + jj][oc];
                cnt++;
            }
        cen[k][oc] = sf / cnt;
        vc[k][oc] = sv / cnt;
    }
    __syncthreads();
    if (p < 25) {
        float s = 0.f;
#pragma unroll
        for (int oc = 0; oc < 6; oc++) s += cen[p][oc] * cen[p][oc];
        cnorm[p] = 1.f / fmaxf(sqrtf(s), 1e-12f);
    }
    __syncthreads();
    float fn2 = 0.f;
#pragma unroll
    for (int oc = 0; oc < 6; oc++) fn2 += fr[oc] * fr[oc];
    float finv = 1.f / fmaxf(sqrtf(fn2), 1e-12f);
    float alpha = alphap[0], beta = betap[0];
    float best = -1.f;
    int bestk = 0;
    for (int k = 0; k < 25; k++) {
        float dot = 0.f;
#pragma unroll
        for (int oc = 0; oc < 6; oc++) dot += cen[k][oc] * fr[oc];
        float xv = beta + alpha * dot * cnorm[k] * finv;
        float s = 1.f / (1.f + __expf(-xv));
        if (s > best) { best = s; bestk = k; }   // first-occurrence argmax
    }
    simb[p] = best;
    kb[p] = bestk;
    __syncthreads();
    if (p < 25) {
        float sum_s = 0.f;
        float av[6];
#pragma unroll
        for (int oc = 0; oc < 6; oc++) av[oc] = vc[p][oc];
        for (int q = 0; q < 64; q++) {
            if (kb[q] == p) {
                float s = simb[q];
                sum_s += s;
#pragma unroll
                for (int oc = 0; oc < 6; oc++) av[oc] += s * vS[q][oc];
            }
        }
        float invd = 1.f / (sum_s + 1.f);
#pragma unroll
        for (int oc = 0; oc < 6; oc++) agg[p][oc] = av[oc] * invd;
    }
    __syncthreads();
    float outp[6];
#pragma unroll
    for (int oc = 0; oc < 6; oc++) outp[oc] = agg[kb[p]][oc] * simb[p];
    float* orow = c96 + ((size_t)b * Lc + lsp) * Cc;
    for (int oo = 0; oo < Cc; oo++) {
        float s = pbp[oo];
#pragma unroll
        for (int oc = 0; oc < 6; oc++) s += outp[oc] * pwp[oo * 6 + oc];
        orow[oo] = s;
    }
}

// ---------------- cluster projection 96 -> 192 ----------------
__global__ __launch_bounds__(256) void clproj_kernel(
    const float* __restrict__ c96, const float* __restrict__ w,
    const float* __restrict__ bias, float* __restrict__ cl) {
    int l = blockIdx.x * 256 + threadIdx.x;
    int o0 = blockIdx.y * 16;
    int b = blockIdx.z;
    const float* row = c96 + ((size_t)b * Lc + l) * Cc;
    float acc[16];
#pragma unroll
    for (int j = 0; j < 16; j++) acc[j] = bias[o0 + j];
#pragma unroll 4
    for (int c = 0; c < Cc; c += 2) {
        float v0 = row[c], v1 = row[c + 1];
#pragma unroll
        for (int j = 0; j < 16; j++) {
            acc[j] += v0 * w[(o0 + j) * Cc + c] + v1 * w[(o0 + j) * Cc + c + 1];
        }
    }
#pragma unroll
    for (int j = 0; j < 16; j++)
        cl[((size_t)b * Lc + l) * Ec + o0 + j] = acc[j];
}

// ---------------- gather y dirs + 3x LayerNorm + branch softmax + out_proj ----------------
__global__ __launch_bounds__(256) void final_kernel(
    const float* __restrict__ ydir, const float* __restrict__ zp,
    const float* __restrict__ cl, const float* __restrict__ bc,
    const float* __restrict__ lnw, const float* __restrict__ lnb,
    const float* __restrict__ woutT, float* __restrict__ out) {
    __shared__ float comb[4][Ec];
    int wave = threadIdx.x >> 6, lane = threadIdx.x & 63;
    int row = blockIdx.x * 4 + wave;
    int b = row >> 12, lp = row & (Lc - 1);
    int iv0 = inv_d0(lp), iv1 = inv_d1(lp), iv2 = inv_d2(lp), iv3 = inv_d3(lp);
    const float* y0 = ydir + ((size_t)(0 * Bc + b) * Lc + iv0) * Ec;
    const float* y1 = ydir + ((size_t)(1 * Bc + b) * Lc + iv1) * Ec;
    const float* y2 = ydir + ((size_t)(2 * Bc + b) * Lc + iv2) * Ec;
    const float* y3 = ydir + ((size_t)(3 * Bc + b) * Lc + iv3) * Ec;
    const float* zr = zp + ((size_t)b * Lc + lp) * Ec;
    const float* cr = cl + ((size_t)b * Lc + lp) * Ec;
    float ys[3], zv[3], cv[3];
    float s1 = 0, s2 = 0, z1 = 0, z2 = 0, c1 = 0, c2 = 0;
#pragma unroll
    for (int t = 0; t < 3; t++) {
        int i = lane + t * 64;
        float v = y0[i] + y1[i] + y2[i] + y3[i];
        ys[t] = v; s1 += v; s2 += v * v;
        float z = zr[i]; zv[t] = z; z1 += z; z2 += z * z;
        float c = cr[i]; cv[t] = c; c1 += c; c2 += c * c;
    }
#pragma unroll
    for (int o = 32; o >= 1; o >>= 1) {
        s1 += __shfl_xor(s1, o, 64); s2 += __shfl_xor(s2, o, 64);
        z1 += __shfl_xor(z1, o, 64); z2 += __shfl_xor(z2, o, 64);
        c1 += __shfl_xor(c1, o, 64); c2 += __shfl_xor(c2, o, 64);
    }
    const float invE = 1.f / (float)Ec;
    float ym = s1 * invE, yvr = rsqrtf(s2 * invE - ym * ym + 1e-5f);
    float zm = z1 * invE, zvr = rsqrtf(z2 * invE - zm * zm + 1e-5f);
    float cm = c1 * invE, cvr = rsqrtf(c2 * invE - cm * cm + 1e-5f);
#pragma unroll
    for (int t = 0; t < 3; t++) {
        int i = lane + t * 64;
        float g = lnw[i], bb = lnb[i];
        float a0 = (ys[t] - ym) * yvr * g + bb;
        float a1 = (zv[t] - zm) * zvr * g + bb;
        float a2 = (cv[t] - cm) * cvr * g + bb;
        float w0 = bc[i], w1 = bc[Ec + i], w2 = bc[2 * Ec + i];
        float mx = fmaxf(w0, fmaxf(w1, w2));
        float e0 = __expf(w0 - mx), e1 = __expf(w1 - mx), e2 = __expf(w2 - mx);
        float inv = 1.f / (e0 + e1 + e2);
        comb[wave][i] = (e0 * a0 + e1 * a1 + e2 * a2) * inv;
    }
    __syncthreads();
    // out_proj: lane = o; woutT[k][o] coalesced; comb[wave][k] LDS broadcast.
    float r0 = 0.f, r1 = 0.f;
#pragma unroll 4
    for (int k = 0; k < Ec; k++) {
        float cvk = comb[wave][k];
        float w0 = woutT[k * Cc + lane];
        float w1 = woutT[k * Cc + 64 + lane];
        r0 += cvk * w0;
        r1 += cvk * w1;
    }
    float* orow = out + (size_t)row * Cc;
    orow[lane] = r0;                      // o = 0..63, coalesced
    if (lane < 32) orow[64 + lane] = r1;  // o = 64..95, coalesced
}

extern "C" void kernel_launch(void* const* d_in, const int* in_sizes, int n_in,
                              void* d_out, int out_size, void* d_ws, size_t ws_size,
                              hipStream_t stream) {
    const float* x       = (const float*)d_in[0];
    const float* wh      = (const float*)d_in[3];
    const float* wv      = (const float*)d_in[4];
    const float* wd1     = (const float*)d_in[5];
    const float* wd2     = (const float*)d_in[6];
    const float* fw      = (const float*)d_in[7];
    const float* ipw     = (const float*)d_in[8];
    const float* xw      = (const float*)d_in[9];
    const float* dtw     = (const float*)d_in[10];
    const float* dtb     = (const float*)d_in[11];
    const float* A_log   = (const float*)d_in[12];
    const float* Dp      = (const float*)d_in[13];
    const float* dirB    = (const float*)d_in[14];
    const float* wout    = (const float*)d_in[15];
    const float* alphap  = (const float*)d_in[16];
    const float* betap   = (const float*)d_in[17];
    const float* fwp     = (const float*)d_in[18];
    const float* fbp     = (const float*)d_in[19];
    const float* vwp     = (const float*)d_in[20];
    const float* vbp     = (const float*)d_in[21];
    const float* pwp     = (const float*)d_in[22];
    const float* pbp     = (const float*)d_in[23];
    const float* clw     = (const float*)d_in[24];
    const float* clb     = (const float*)d_in[25];
    const float* bc      = (const float*)d_in[26];
    const float* lnw     = (const float*)d_in[27];
    const float* lnb     = (const float*)d_in[28];
    float* out = (float*)d_out;

    float* wsf = (float*)d_ws;
    size_t off = 0;
    int* ord      = (int*)wsf;             off += 4 * Lc;                 // 64 KB
    float* cat    = wsf + off;             off += (size_t)Bc * CATc * Lc; // 24 MB (reused as ydir)
    float* xconv  = wsf + off;             off += (size_t)Bc * Cc * Lc;   // 3 MB
    float* xp     = wsf + off;             off += (size_t)Bc * Lc * Ec;   // 6 MB (reused as c96)
    float* zpb    = wsf + off;             off += (size_t)Bc * Lc * Ec;   // 6 MB
    float* deltab = wsf + off;             off += (size_t)Bc * Lc * Ec;   // 6 MB (reused as cl)
    float* Bst    = wsf + off;             off += (size_t)Bc * Lc * Nc;   // 0.5 MB
    float* Cst    = wsf + off;             off += (size_t)Bc * Lc * Nc;   // 0.5 MB
    float* hend   = wsf + off;             off += (size_t)4 * Bc * NCH * Ec * Nc; // 12.6 MB
    float* Pend   = wsf + off;             off += (size_t)Bc * NCH * Ec * Nc;     // 3.1 MB
    float* woutT  = wsf + off;             off += (size_t)Ec * Cc + 64;           // 74 KB (+64 pad)
    // total ≈ 64.3 MB
    float* ydir = cat;     // cat dead after fuse; same size as ydir
    float* c96  = xp;      // xp dead after scan_part2 (stream-serialized)
    float* cl   = deltab;  // delta dead after scan_part2
    // fuse 8-way split-K partials: 8*Bc*Cc*Lc = 6,291,456 floats — spans
    // xp..hend-prefix (xp/zpb/delta/Bst/Cst written only after fuse_reduce;
    // xT in hend prefix dead after conv; all stream-serialized)
    float* pxconv = xp;
    // xT (0.79M floats) aliases hend: dead until scan_part1, conv runs first
    float* xT = hend;

    order_kernel<<<16, 256, 0, stream>>>(ord);
    wt_kernel<<<72, 256, 0, stream>>>(wout, woutT);
    xt_kernel<<<dim3(128, 2), 256, 0, stream>>>(x, xT);
    conv_kernel<<<dim3(16, 96, 2), 256, 0, stream>>>(xT, wh, wv, wd1, wd2, cat);
    fuse_part<<<dim3(16, 6, 16), 256, 0, stream>>>(cat, fw, pxconv);
    fuse_reduce<<<3072, 256, 0, stream>>>(pxconv, xconv);
    inproj_kernel<<<dim3(16, 24, 2), 256, 0, stream>>>(xconv, ipw, xp, zpb);
    xdbl_kernel<<<256, 256, 0, stream>>>(xp, xw, dtw, dtb, deltab, Bst, Cst);
    scan_part1<<<dim3(NCH, 2, 4), 192, 0, stream>>>(xp, ord, deltab, Bst,
                                                    A_log, dirB, hend, Pend);
    scan_mid<<<96, 256, 0, stream>>>(hend, Pend);
    scan_part2<<<dim3(NCH, 2, 4), 192, 0, stream>>>(xp, ord, deltab, Bst, Cst,
                                                    A_log, Dp, dirB, hend, ydir);
    cluster_kernel<<<128, 64, 0, stream>>>(xconv, fwp, fbp, vwp, vbp, pwp, pbp,
                                           alphap, betap, c96);
    clproj_kernel<<<dim3(16, 12, 2), 256, 0, stream>>>(c96, clw, clb, cl);
    final_kernel<<<2048, 256, 0, stream>>>(ydir, zpb, cl, bc, lnw, lnb, woutT, out);
}

// Round 17
// 426.412 us; speedup vs baseline: 1.1327x; 1.0372x over previous
//
#include <hip/hip_runtime.h>
#include <hip/hip_bf16.h>

#define Bc   2
#define Hc   64
#define Wc   64
#define Lc   4096
#define Cc   96
#define Ec   192
#define Nc   16
#define CATc 768
#define CHUNK 32
#define NCH  128
#define XJ   38

// ---------------- scan-order closed forms (H=W=64) ----------------
__device__ __forceinline__ int inv_d0(int l) {           // bottom-up boustrophedon rows
    int i = l >> 6, j = l & 63;
    int k = 63 - i;
    int m = (k & 1) ? (63 - j) : j;
    return k * 64 + m;
}
__device__ __forceinline__ int inv_d1(int l) {           // left-right boustrophedon cols
    int i = l >> 6, j = l & 63;
    int m = (j & 1) ? (63 - i) : i;
    return j * 64 + m;
}
__device__ __forceinline__ int diag_off(int d) {
    return (d <= 63) ? (d * (d + 1) / 2) : (4096 - (127 - d) * (128 - d) / 2);
}
__device__ __forceinline__ int inv_d2(int l) {           // diagonals
    int i = l >> 6, j = l & 63;
    int d = i + j;
    int st = d > 63 ? d - 63 : 0;
    return diag_off(d) + (i - st);
}
__device__ __forceinline__ int inv_d3(int l) {           // anti-diagonals
    int i = l >> 6, jj = l & 63;
    int j = 63 - jj;
    int d = i + j;
    int st = d > 63 ? d - 63 : 0;
    return diag_off(d) + (i - st);
}

// setup: blocks 0..15 build scan orders; blocks 16..87 transpose wout
__global__ __launch_bounds__(256) void setup_kernel(
    int* __restrict__ ord, const float* __restrict__ wout,
    float* __restrict__ woutT) {
    if (blockIdx.x < 16) {
        int l = blockIdx.x * 256 + threadIdx.x;
        ord[0 * Lc + inv_d0(l)] = l;
        ord[1 * Lc + inv_d1(l)] = l;
        ord[2 * Lc + inv_d2(l)] = l;
        ord[3 * Lc + inv_d3(l)] = l;
    } else {
        int idx = (blockIdx.x - 16) * 256 + threadIdx.x;
        if (idx < Ec * Cc) {
            int k = idx / Cc, o = idx % Cc;
            woutT[idx] = wout[o * Ec + k];
        }
    }
}

// ---------------- directional convs + SiLU -> cat [B,768,L] ----------------
__global__ __launch_bounds__(256) void conv_kernel(
    const float* __restrict__ x, const float* __restrict__ wh,
    const float* __restrict__ wv, const float* __restrict__ wd1,
    const float* __restrict__ wd2, float* __restrict__ cat) {
    int tile = blockIdx.x, ic = blockIdx.y, b = blockIdx.z;
    int th0 = (tile >> 2) * 16, tw0 = (tile & 3) * 16;
    __shared__ float S[22][24];
    int tid = threadIdx.x;
    for (int idx = tid; idx < 22 * 22; idx += 256) {
        int r = idx / 22, c = idx % 22;
        int gh = th0 + r - 3, gw = tw0 + c - 3;
        float v = 0.f;
        if (gh >= 0 && gh < 64 && gw >= 0 && gw < 64)
            v = x[((size_t)b * Lc + gh * 64 + gw) * Cc + ic];
        S[r][c] = v;
    }
    __syncthreads();
    int ti = tid >> 4, tj = tid & 15;
    int pix = (th0 + ti) * 64 + (tw0 + tj);
    for (int s = 0; s < 2; s++) {
        int o = 2 * ic + s;
        float ah = 0.f, av = 0.f, a1 = 0.f, a2 = 0.f;
#pragma unroll
        for (int t = 0; t < 7; t++) {
            ah += S[ti + 3][tj + t] * wh[o * 7 + t];
            av += S[ti + t][tj + 3] * wv[o * 7 + t];
        }
#pragma unroll
        for (int r = 0; r < 7; r++)
#pragma unroll
            for (int c2 = 0; c2 < 7; c2++) {
                float sv = S[ti + r][tj + c2];
                a1 += sv * wd1[o * 49 + r * 7 + c2];
                a2 += sv * wd2[o * 49 + r * 7 + c2];
            }
        cat[((size_t)b * CATc + 0 * Ec + o) * Lc + pix] = ah / (1.f + __expf(-ah));
        cat[((size_t)b * CATc + 1 * Ec + o) * Lc + pix] = av / (1.f + __expf(-av));
        cat[((size_t)b * CATc + 2 * Ec + o) * Lc + pix] = a1 / (1.f + __expf(-a1));
        cat[((size_t)b * CATc + 3 * Ec + o) * Lc + pix] = a2 / (1.f + __expf(-a2));
    }
}

// ---------------- fuse split-K: 8 K-chunks x 12 o-groups of 8 (max TLP) ----------------
// affine indexing (scalar-offset codegen); unroll 4 = verified knee
__global__ __launch_bounds__(256) void fuse_part(
    const float* __restrict__ cat, const float* __restrict__ fw,
    float* __restrict__ pxconv) {
    int l = blockIdx.x * 256 + threadIdx.x;
    int o0 = blockIdx.y * 8;
    int cs = blockIdx.z >> 1, b = blockIdx.z & 1;
    int c0 = cs * 96;
    float acc[8];
#pragma unroll
    for (int j = 0; j < 8; j++) acc[j] = 0.f;
#pragma unroll 4
    for (int c = c0; c < c0 + 96; c += 2) {
        float v0 = cat[((size_t)b * CATc + c) * Lc + l];
        float v1 = cat[((size_t)b * CATc + c + 1) * Lc + l];
#pragma unroll
        for (int j = 0; j < 8; j++) {
            acc[j] += v0 * fw[(o0 + j) * CATc + c] + v1 * fw[(o0 + j) * CATc + c + 1];
        }
    }
#pragma unroll
    for (int j = 0; j < 8; j++)
        pxconv[(((size_t)cs * Bc + b) * Cc + o0 + j) * Lc + l] = acc[j];
}

__global__ __launch_bounds__(256) void fuse_reduce(
    const float* __restrict__ pxconv, float* __restrict__ xconv) {
    size_t idx = ((size_t)blockIdx.x * 256 + threadIdx.x) * 4;   // float4 over Bc*Cc*Lc
    const size_t stride = (size_t)Bc * Cc * Lc;
    float4 s = *(const float4*)(pxconv + idx);
#pragma unroll
    for (int k = 1; k < 8; k++) {
        float4 v = *(const float4*)(pxconv + idx + (size_t)k * stride);
        s.x += v.x; s.y += v.y; s.z += v.z; s.w += v.w;
    }
    *(float4*)(xconv + idx) = s;
}

// ---------------- in_proj: xp/zp [B,L,192] ----------------
__global__ __launch_bounds__(256) void inproj_kernel(
    const float* __restrict__ xconv, const float* __restrict__ w,
    float* __restrict__ xp, float* __restrict__ zp) {
    int l = blockIdx.x * 256 + threadIdx.x;
    int o0 = blockIdx.y * 16;
    int b = blockIdx.z;
    float acc[16];
#pragma unroll
    for (int j = 0; j < 16; j++) acc[j] = 0.f;
#pragma unroll 4
    for (int c = 0; c < Cc; c += 2) {
        float v0 = xconv[((size_t)b * Cc + c) * Lc + l];
        float v1 = xconv[((size_t)b * Cc + c + 1) * Lc + l];
#pragma unroll
        for (int j = 0; j < 16; j++) {
            acc[j] += v0 * w[(o0 + j) * Cc + c] + v1 * w[(o0 + j) * Cc + c + 1];
        }
    }
#pragma unroll
    for (int j = 0; j < 16; j++) {
        int o = o0 + j;
        if (o < Ec) xp[((size_t)b * Lc + l) * Ec + o] = acc[j];
        else        zp[((size_t)b * Lc + l) * Ec + (o - Ec)] = acc[j];
    }
}

// ---------------- xdbl GEMM + fused delta softplus ----------------
__global__ __launch_bounds__(256) void xdbl_kernel(
    const float* __restrict__ xp, const float* __restrict__ xw,
    const float* __restrict__ dtw, const float* __restrict__ dtb,
    float* __restrict__ delta, float* __restrict__ Bst, float* __restrict__ Cst) {
    int rb = blockIdx.x;                 // 256 blocks, 32 rows each
    __shared__ float S[32][193];         // pad 193: conflict-free
    __shared__ float dt6s[32][6];
    const float* src = xp + (size_t)rb * 32 * Ec;
    for (int idx = threadIdx.x; idx < 32 * Ec / 4; idx += 256) {
        int fl = idx * 4;
        int r = fl / Ec, c = fl % Ec;
        float4 v = *(const float4*)(src + fl);
        S[r][c] = v.x; S[r][c + 1] = v.y; S[r][c + 2] = v.z; S[r][c + 3] = v.w;
    }
    __syncthreads();
    for (int t = threadIdx.x; t < 32 * XJ; t += 256) {
        int r = t / XJ, j = t % XJ;
        const float* wrow = xw + j * Ec;
        float s = 0.f;
#pragma unroll 4
        for (int c = 0; c < Ec; c++) s += S[r][c] * wrow[c];
        int row = rb * 32 + r;
        if (j < 6)       dt6s[r][j] = s;
        else if (j < 22) Bst[row * Nc + (j - 6)] = s;
        else             Cst[row * Nc + (j - 22)] = s;
    }
    __syncthreads();
    // delta: softplus(dt6 @ dtw^T + 2*dtb) for 32 rows x 192 e
    for (int idx = threadIdx.x; idx < 32 * Ec; idx += 256) {
        int r = idx / Ec, e = idx % Ec;
        const float* w = dtw + e * 6;
        float s = 2.f * dtb[e];
#pragma unroll
        for (int rr = 0; rr < 6; rr++) s += dt6s[r][rr] * w[rr];
        delta[(size_t)(rb * 32 + r) * Ec + e] = (s > 20.f) ? s : log1pf(__expf(s));
    }
}

// ============ chunked selective scan, thread-owns-e layout ============
// hend layout: [d][b][chunk][n][e]  (chunk stride 3072, n stride 192)
// Pend layout: [b][chunk][n][e]

__global__ __launch_bounds__(192) void scan_part1(
    const float* __restrict__ xp, const int* __restrict__ ord,
    const float* __restrict__ delta, const float* __restrict__ Bst,
    const float* __restrict__ A_log, const float* __restrict__ dirB,
    float* __restrict__ hend, float* __restrict__ Pend) {
    int chunk = blockIdx.x, b = blockIdx.y, d = blockIdx.z;
    int e = threadIdx.x;                 // 0..191
    __shared__ int lord[CHUNK];
    if (threadIdx.x < CHUNK) lord[threadIdx.x] = ord[d * Lc + chunk * CHUNK + threadIdx.x];
    __syncthreads();
    float Aen[Nc], h[Nc], P[Nc], Bd[Nc];
#pragma unroll
    for (int n = 0; n < Nc; n++) {
        Aen[n] = -__expf(A_log[e * Nc + n]);
        Bd[n] = dirB[d * Nc + n];        // block-uniform -> scalar
        h[n] = 0.f; P[n] = 1.f;
    }
    const float* dl  = delta + (size_t)b * Lc * Ec;
    const float* xpb = xp + (size_t)b * Lc * Ec;
    const float* Bb  = Bst + (size_t)b * Lc * Nc;
    int l0 = chunk * CHUNK;
#pragma unroll 2
    for (int t = 0; t < CHUNK; t++) {
        int l = l0 + t;
        float de = dl[(size_t)l * Ec + e];                 // coalesced
        float uu = xpb[(size_t)lord[t] * Ec + e];          // coalesced (uniform row)
        float dub = de * uu;
        const float* Brow = Bb + (size_t)l * Nc;           // uniform -> scalar loads
#pragma unroll
        for (int n = 0; n < Nc; n++) {
            float dA = __expf(de * Aen[n]);
            h[n] = dA * h[n] + dub * (Brow[n] + Bd[n]);
            P[n] *= dA;
        }
    }
    size_t base = ((size_t)(d * Bc + b) * NCH + chunk) * 3072 + e;
#pragma unroll
    for (int n = 0; n < Nc; n++) hend[base + n * Ec] = h[n];
    if (d == 0) {
        size_t pb = ((size_t)b * NCH + chunk) * 3072 + e;
#pragma unroll
        for (int n = 0; n < Nc; n++) Pend[pb + n * Ec] = P[n];
    }
}

__global__ __launch_bounds__(256) void scan_mid(
    float* __restrict__ hend, const float* __restrict__ Pend) {
    int blk = blockIdx.x;            // (d*2+b)*12 + sub
    int sub = blk % 12, db = blk / 12;
    int b = db & 1;
    int pair = sub * 256 + threadIdx.x;   // 0..3071 = (n,e) flat
    size_t base  = (size_t)db * NCH * 3072 + pair;
    size_t pbase = (size_t)b * NCH * 3072 + pair;
    float h = 0.f;
    for (int c = 0; c < NCH; c++) {
        float hc = hend[base + (size_t)c * 3072];
        float P  = Pend[pbase + (size_t)c * 3072];
        hend[base + (size_t)c * 3072] = h;   // h_in for chunk c
        h = P * h + hc;
    }
}

__global__ __launch_bounds__(192) void scan_part2(
    const float* __restrict__ xp, const int* __restrict__ ord,
    const float* __restrict__ delta, const float* __restrict__ Bst,
    const float* __restrict__ Cst, const float* __restrict__ A_log,
    const float* __restrict__ Dp, const float* __restrict__ dirB,
    const float* __restrict__ hend, float* __restrict__ ydir) {
    int chunk = blockIdx.x, b = blockIdx.y, d = blockIdx.z;
    int e = threadIdx.x;                 // 0..191
    __shared__ int lord[CHUNK];
    if (threadIdx.x < CHUNK) lord[threadIdx.x] = ord[d * Lc + chunk * CHUNK + threadIdx.x];
    __syncthreads();
    float Aen[Nc], h[Nc], Bd[Nc];
    size_t base = ((size_t)(d * Bc + b) * NCH + chunk) * 3072 + e;
#pragma unroll
    for (int n = 0; n < Nc; n++) {
        Aen[n] = -__expf(A_log[e * Nc + n]);
        Bd[n] = dirB[d * Nc + n];
        h[n] = hend[base + n * Ec];
    }
    float De = Dp[e];
    const float* dl  = delta + (size_t)b * Lc * Ec;
    const float* xpb = xp + (size_t)b * Lc * Ec;
    const float* Bb  = Bst + (size_t)b * Lc * Nc;
    const float* Cb  = Cst + (size_t)b * Lc * Nc;
    float* yo = ydir + ((size_t)(d * Bc + b) * Lc) * Ec + e;
    int l0 = chunk * CHUNK;
#pragma unroll 2
    for (int t = 0; t < CHUNK; t++) {
        int l = l0 + t;
        float de = dl[(size_t)l * Ec + e];
        float uu = xpb[(size_t)lord[t] * Ec + e];
        float dub = de * uu;
        const float* Brow = Bb + (size_t)l * Nc;
        const float* Crow = Cb + (size_t)l * Nc;
        float acc = De * uu;
#pragma unroll
        for (int n = 0; n < Nc; n++) {
            float dA = __expf(de * Aen[n]);
            h[n] = dA * h[n] + dub * (Brow[n] + Bd[n]);
            acc += h[n] * Crow[n];
        }
        yo[(size_t)l * Ec] = acc;                           // coalesced
    }
}

// ---------------- local cluster: one block per 8x8 tile ----------------
__global__ __launch_bounds__(64) void cluster_kernel(
    const float* __restrict__ xconv,
    const float* __restrict__ fwp, const float* __restrict__ fbp,
    const float* __restrict__ vwp, const float* __restrict__ vbp,
    const float* __restrict__ pwp, const float* __restrict__ pbp,
    const float* __restrict__ alphap, const float* __restrict__ betap,
    float* __restrict__ c96) {
    int g = blockIdx.x;
    int b = g >> 6, Wg = (g >> 3) & 7, Hg = g & 7;
    int p = threadIdx.x;
    int wi = p >> 3, hj = p & 7;
    int lsp = (Wg * 8 + wi) * 64 + (Hg * 8 + hj);
    __shared__ float fS[64][6], vS[64][6];
    __shared__ float cen[25][6], vc[25][6], cnorm[25];
    __shared__ float simb[64];
    __shared__ int kb[64];
    __shared__ float agg[25][6];
    float fr[6], vr[6];
#pragma unroll
    for (int oc = 0; oc < 6; oc++) { fr[oc] = fbp[oc]; vr[oc] = vbp[oc]; }
    for (int c = 0; c < 48; c++) {
        float v1 = xconv[((size_t)b * Cc + c) * Lc + lsp];
        float v2 = xconv[((size_t)b * Cc + 48 + c) * Lc + lsp];
#pragma unroll
        for (int oc = 0; oc < 6; oc++) {
            fr[oc] += v1 * fwp[oc * 48 + c];
            vr[oc] += v2 * vwp[oc * 48 + c];
        }
    }
#pragma unroll
    for (int oc = 0; oc < 6; oc++) { fS[p][oc] = fr[oc]; vS[p][oc] = vr[oc]; }
    __syncthreads();
    // adaptive-pool bins for 8->5
    const int bs[5] = {0, 1, 3, 4, 6}, be[5] = {2, 4, 5, 7, 8};
    for (int t = p; t < 150; t += 64) {
        int k = t / 6, oc = t % 6;
        int ki = k / 5, kj = k % 5;
        float sf = 0.f, sv = 0.f;
        int cnt = 0;
        for (int ii = bs[ki]; ii < be[ki]; ii++)
            for (int jj = bs[kj]; jj < be[kj]; jj++) {
                sf += fS[ii * 8 + jj][oc];
                sv += vS[ii * 8 + jj][oc];
                cnt++;
            }
        cen[k][oc] = sf / cnt;
        vc[k][oc] = sv / cnt;
    }
    __syncthreads();
    if (p < 25) {
        float s = 0.f;
#pragma unroll
        for (int oc = 0; oc < 6; oc++) s += cen[p][oc] * cen[p][oc];
        cnorm[p] = 1.f / fmaxf(sqrtf(s), 1e-12f);
    }
    __syncthreads();
    float fn2 = 0.f;
#pragma unroll
    for (int oc = 0; oc < 6; oc++) fn2 += fr[oc] * fr[oc];
    float finv = 1.f / fmaxf(sqrtf(fn2), 1e-12f);
    float alpha = alphap[0], beta = betap[0];
    float best = -1.f;
    int bestk = 0;
    for (int k = 0; k < 25; k++) {
        float dot = 0.f;
#pragma unroll
        for (int oc = 0; oc < 6; oc++) dot += cen[k][oc] * fr[oc];
        float xv = beta + alpha * dot * cnorm[k] * finv;
        float s = 1.f / (1.f + __expf(-xv));
        if (s > best) { best = s; bestk = k; }   // first-occurrence argmax
    }
    simb[p] = best;
    kb[p] = bestk;
    __syncthreads();
    if (p < 25) {
        float sum_s = 0.f;
        float av[6];
#pragma unroll
        for (int oc = 0; oc < 6; oc++) av[oc] = vc[p][oc];
        for (int q = 0; q < 64; q++) {
            if (kb[q] == p) {
                float s = simb[q];
                sum_s += s;
#pragma unroll
                for (int oc = 0; oc < 6; oc++) av[oc] += s * vS[q][oc];
            }
        }
        float invd = 1.f / (sum_s + 1.f);
#pragma unroll
        for (int oc = 0; oc < 6; oc++) agg[p][oc] = av[oc] * invd;
    }
    __syncthreads();
    float outp[6];
#pragma unroll
    for (int oc = 0; oc < 6; oc++) outp[oc] = agg[kb[p]][oc] * simb[p];
    float* orow = c96 + ((size_t)b * Lc + lsp) * Cc;
    for (int oo = 0; oo < Cc; oo++) {
        float s = pbp[oo];
#pragma unroll
        for (int oc = 0; oc < 6; oc++) s += outp[oc] * pwp[oo * 6 + oc];
        orow[oo] = s;
    }
}

// ---------------- cluster projection 96 -> 192 ----------------
__global__ __launch_bounds__(256) void clproj_kernel(
    const float* __restrict__ c96, const float* __restrict__ w,
    const float* __restrict__ bias, float* __restrict__ cl) {
    int l = blockIdx.x * 256 + threadIdx.x;
    int o0 = blockIdx.y * 16;
    int b = blockIdx.z;
    const float* row = c96 + ((size_t)b * Lc + l) * Cc;
    float acc[16];
#pragma unroll
    for (int j = 0; j < 16; j++) acc[j] = bias[o0 + j];
#pragma unroll 4
    for (int c = 0; c < Cc; c += 2) {
        float v0 = row[c], v1 = row[c + 1];
#pragma unroll
        for (int j = 0; j < 16; j++) {
            acc[j] += v0 * w[(o0 + j) * Cc + c] + v1 * w[(o0 + j) * Cc + c + 1];
        }
    }
#pragma unroll
    for (int j = 0; j < 16; j++)
        cl[((size_t)b * Lc + l) * Ec + o0 + j] = acc[j];
}

// ---------------- gather y dirs + 3x LayerNorm + branch softmax + out_proj ----------------
__global__ __launch_bounds__(256) void final_kernel(
    const float* __restrict__ ydir, const float* __restrict__ zp,
    const float* __restrict__ cl, const float* __restrict__ bc,
    const float* __restrict__ lnw, const float* __restrict__ lnb,
    const float* __restrict__ woutT, float* __restrict__ out) {
    __shared__ float comb[4][Ec];
    int wave = threadIdx.x >> 6, lane = threadIdx.x & 63;
    int row = blockIdx.x * 4 + wave;
    int b = row >> 12, lp = row & (Lc - 1);
    int iv0 = inv_d0(lp), iv1 = inv_d1(lp), iv2 = inv_d2(lp), iv3 = inv_d3(lp);
    const float* y0 = ydir + ((size_t)(0 * Bc + b) * Lc + iv0) * Ec;
    const float* y1 = ydir + ((size_t)(1 * Bc + b) * Lc + iv1) * Ec;
    const float* y2 = ydir + ((size_t)(2 * Bc + b) * Lc + iv2) * Ec;
    const float* y3 = ydir + ((size_t)(3 * Bc + b) * Lc + iv3) * Ec;
    const float* zr = zp + ((size_t)b * Lc + lp) * Ec;
    const float* cr = cl + ((size_t)b * Lc + lp) * Ec;
    float ys[3], zv[3], cv[3];
    float s1 = 0, s2 = 0, z1 = 0, z2 = 0, c1 = 0, c2 = 0;
#pragma unroll
    for (int t = 0; t < 3; t++) {
        int i = lane + t * 64;
        float v = y0[i] + y1[i] + y2[i] + y3[i];
        ys[t] = v; s1 += v; s2 += v * v;
        float z = zr[i]; zv[t] = z; z1 += z; z2 += z * z;
        float c = cr[i]; cv[t] = c; c1 += c; c2 += c * c;
    }
#pragma unroll
    for (int o = 32; o >= 1; o >>= 1) {
        s1 += __shfl_xor(s1, o, 64); s2 += __shfl_xor(s2, o, 64);
        z1 += __shfl_xor(z1, o, 64); z2 += __shfl_xor(z2, o, 64);
        c1 += __shfl_xor(c1, o, 64); c2 += __shfl_xor(c2, o, 64);
    }
    const float invE = 1.f / (float)Ec;
    float ym = s1 * invE, yvr = rsqrtf(s2 * invE - ym * ym + 1e-5f);
    float zm = z1 * invE, zvr = rsqrtf(z2 * invE - zm * zm + 1e-5f);
    float cm = c1 * invE, cvr = rsqrtf(c2 * invE - cm * cm + 1e-5f);
#pragma unroll
    for (int t = 0; t < 3; t++) {
        int i = lane + t * 64;
        float g = lnw[i], bb = lnb[i];
        float a0 = (ys[t] - ym) * yvr * g + bb;
        float a1 = (zv[t] - zm) * zvr * g + bb;
        float a2 = (cv[t] - cm) * cvr * g + bb;
        float w0 = bc[i], w1 = bc[Ec + i], w2 = bc[2 * Ec + i];
        float mx = fmaxf(w0, fmaxf(w1, w2));
        float e0 = __expf(w0 - mx), e1 = __expf(w1 - mx), e2 = __expf(w2 - mx);
        float inv = 1.f / (e0 + e1 + e2);
        comb[wave][i] = (e0 * a0 + e1 * a1 + e2 * a2) * inv;
    }
    __syncthreads();
    // out_proj: lane = o; woutT[k][o] coalesced; comb[wave][k] LDS broadcast.
    float r0 = 0.f, r1 = 0.f;
#pragma unroll 4
    for (int k = 0; k < Ec; k++) {
        float cvk = comb[wave][k];
        float w0 = woutT[k * Cc + lane];
        float w1 = woutT[k * Cc + 64 + lane];
        r0 += cvk * w0;
        r1 += cvk * w1;
    }
    float* orow = out + (size_t)row * Cc;
    orow[lane] = r0;                      // o = 0..63, coalesced
    if (lane < 32) orow[64 + lane] = r1;  // o = 64..95, coalesced
}

extern "C" void kernel_launch(void* const* d_in, const int* in_sizes, int n_in,
                              void* d_out, int out_size, void* d_ws, size_t ws_size,
                              hipStream_t stream) {
    const float* x       = (const float*)d_in[0];
    const float* wh      = (const float*)d_in[3];
    const float* wv      = (const float*)d_in[4];
    const float* wd1     = (const float*)d_in[5];
    const float* wd2     = (const float*)d_in[6];
    const float* fw      = (const float*)d_in[7];
    const float* ipw     = (const float*)d_in[8];
    const float* xw      = (const float*)d_in[9];
    const float* dtw     = (const float*)d_in[10];
    const float* dtb     = (const float*)d_in[11];
    const float* A_log   = (const float*)d_in[12];
    const float* Dp      = (const float*)d_in[13];
    const float* dirB    = (const float*)d_in[14];
    const float* wout    = (const float*)d_in[15];
    const float* alphap  = (const float*)d_in[16];
    const float* betap   = (const float*)d_in[17];
    const float* fwp     = (const float*)d_in[18];
    const float* fbp     = (const float*)d_in[19];
    const float* vwp     = (const float*)d_in[20];
    const float* vbp     = (const float*)d_in[21];
    const float* pwp     = (const float*)d_in[22];
    const float* pbp     = (const float*)d_in[23];
    const float* clw     = (const float*)d_in[24];
    const float* clb     = (const float*)d_in[25];
    const float* bc      = (const float*)d_in[26];
    const float* lnw     = (const float*)d_in[27];
    const float* lnb     = (const float*)d_in[28];
    float* out = (float*)d_out;

    float* wsf = (float*)d_ws;
    size_t off = 0;
    int* ord      = (int*)wsf;             off += 4 * Lc;                 // 64 KB
    float* cat    = wsf + off;             off += (size_t)Bc * CATc * Lc; // 24 MB (reused as ydir)
    float* xconv  = wsf + off;             off += (size_t)Bc * Cc * Lc;   // 3 MB
    float* xp     = wsf + off;             off += (size_t)Bc * Lc * Ec;   // 6 MB (reused as c96)
    float* zpb    = wsf + off;             off += (size_t)Bc * Lc * Ec;   // 6 MB
    float* deltab = wsf + off;             off += (size_t)Bc * Lc * Ec;   // 6 MB (reused as cl)
    float* Bst    = wsf + off;             off += (size_t)Bc * Lc * Nc;   // 0.5 MB
    float* Cst    = wsf + off;             off += (size_t)Bc * Lc * Nc;   // 0.5 MB
    float* hend   = wsf + off;             off += (size_t)4 * Bc * NCH * Ec * Nc; // 12.6 MB
    float* Pend   = wsf + off;             off += (size_t)Bc * NCH * Ec * Nc;     // 3.1 MB
    float* woutT  = wsf + off;             off += (size_t)Ec * Cc + 64;           // 74 KB (+64 pad)
    // total ≈ 64.3 MB
    float* ydir = cat;     // cat dead after fuse; same size as ydir
    float* c96  = xp;      // xp dead after scan_part2 (stream-serialized)
    float* cl   = deltab;  // delta dead after scan_part2
    // fuse 8-way split-K partials: 8*Bc*Cc*Lc = 6,291,456 floats — spans
    // xp..hend-prefix (xp/zpb/delta/Bst/Cst written only after fuse_reduce;
    // all stream-serialized)
    float* pxconv = xp;

    setup_kernel<<<88, 256, 0, stream>>>(ord, wout, woutT);
    conv_kernel<<<dim3(16, 96, 2), 256, 0, stream>>>(x, wh, wv, wd1, wd2, cat);
    fuse_part<<<dim3(16, 12, 16), 256, 0, stream>>>(cat, fw, pxconv);
    fuse_reduce<<<768, 256, 0, stream>>>(pxconv, xconv);
    inproj_kernel<<<dim3(16, 24, 2), 256, 0, stream>>>(xconv, ipw, xp, zpb);
    xdbl_kernel<<<256, 256, 0, stream>>>(xp, xw, dtw, dtb, deltab, Bst, Cst);
    scan_part1<<<dim3(NCH, 2, 4), 192, 0, stream>>>(xp, ord, deltab, Bst,
                                                    A_log, dirB, hend, Pend);
    scan_mid<<<96, 256, 0, stream>>>(hend, Pend);
    scan_part2<<<dim3(NCH, 2, 4), 192, 0, stream>>>(xp, ord, deltab, Bst, Cst,
                                                    A_log, Dp, dirB, hend, ydir);
    cluster_kernel<<<128, 64, 0, stream>>>(xconv, fwp, fbp, vwp, vbp, pwp, pbp,
                                           alphap, betap, c96);
    clproj_kernel<<<dim3(16, 12, 2), 256, 0, stream>>>(c96, clw, clb, cl);
    final_kernel<<<2048, 256, 0, stream>>>(ydir, zpb, cl, bc, lnw, lnb, woutT, out);
}

// Round 18
// 416.433 us; speedup vs baseline: 1.1599x; 1.0240x over previous
//
#include <hip/hip_runtime.h>
#include <hip/hip_bf16.h>

#define Bc   2
#define Hc   64
#define Wc   64
#define Lc   4096
#define Cc   96
#define Ec   192
#define Nc   16
#define CATc 768
#define CHUNK 16
#define NCH  256
#define XJ   38

// ---------------- scan-order closed forms (H=W=64) ----------------
__device__ __forceinline__ int inv_d0(int l) {           // bottom-up boustrophedon rows
    int i = l >> 6, j = l & 63;
    int k = 63 - i;
    int m = (k & 1) ? (63 - j) : j;
    return k * 64 + m;
}
__device__ __forceinline__ int inv_d1(int l) {           // left-right boustrophedon cols
    int i = l >> 6, j = l & 63;
    int m = (j & 1) ? (63 - i) : i;
    return j * 64 + m;
}
__device__ __forceinline__ int diag_off(int d) {
    return (d <= 63) ? (d * (d + 1) / 2) : (4096 - (127 - d) * (128 - d) / 2);
}
__device__ __forceinline__ int inv_d2(int l) {           // diagonals
    int i = l >> 6, j = l & 63;
    int d = i + j;
    int st = d > 63 ? d - 63 : 0;
    return diag_off(d) + (i - st);
}
__device__ __forceinline__ int inv_d3(int l) {           // anti-diagonals
    int i = l >> 6, jj = l & 63;
    int j = 63 - jj;
    int d = i + j;
    int st = d > 63 ? d - 63 : 0;
    return diag_off(d) + (i - st);
}

// setup: blocks 0..15 build scan orders; blocks 16..87 transpose wout
__global__ __launch_bounds__(256) void setup_kernel(
    int* __restrict__ ord, const float* __restrict__ wout,
    float* __restrict__ woutT) {
    if (blockIdx.x < 16) {
        int l = blockIdx.x * 256 + threadIdx.x;
        ord[0 * Lc + inv_d0(l)] = l;
        ord[1 * Lc + inv_d1(l)] = l;
        ord[2 * Lc + inv_d2(l)] = l;
        ord[3 * Lc + inv_d3(l)] = l;
    } else {
        int idx = (blockIdx.x - 16) * 256 + threadIdx.x;
        if (idx < Ec * Cc) {
            int k = idx / Cc, o = idx % Cc;
            woutT[idx] = wout[o * Ec + k];
        }
    }
}

// ---------------- directional convs + SiLU -> cat [B,768,L] ----------------
__global__ __launch_bounds__(256) void conv_kernel(
    const float* __restrict__ x, const float* __restrict__ wh,
    const float* __restrict__ wv, const float* __restrict__ wd1,
    const float* __restrict__ wd2, float* __restrict__ cat) {
    int tile = blockIdx.x, ic = blockIdx.y, b = blockIdx.z;
    int th0 = (tile >> 2) * 16, tw0 = (tile & 3) * 16;
    __shared__ float S[22][24];
    int tid = threadIdx.x;
    for (int idx = tid; idx < 22 * 22; idx += 256) {
        int r = idx / 22, c = idx % 22;
        int gh = th0 + r - 3, gw = tw0 + c - 3;
        float v = 0.f;
        if (gh >= 0 && gh < 64 && gw >= 0 && gw < 64)
            v = x[((size_t)b * Lc + gh * 64 + gw) * Cc + ic];
        S[r][c] = v;
    }
    __syncthreads();
    int ti = tid >> 4, tj = tid & 15;
    int pix = (th0 + ti) * 64 + (tw0 + tj);
    for (int s = 0; s < 2; s++) {
        int o = 2 * ic + s;
        float ah = 0.f, av = 0.f, a1 = 0.f, a2 = 0.f;
#pragma unroll
        for (int t = 0; t < 7; t++) {
            ah += S[ti + 3][tj + t] * wh[o * 7 + t];
            av += S[ti + t][tj + 3] * wv[o * 7 + t];
        }
#pragma unroll
        for (int r = 0; r < 7; r++)
#pragma unroll
            for (int c2 = 0; c2 < 7; c2++) {
                float sv = S[ti + r][tj + c2];
                a1 += sv * wd1[o * 49 + r * 7 + c2];
                a2 += sv * wd2[o * 49 + r * 7 + c2];
            }
        cat[((size_t)b * CATc + 0 * Ec + o) * Lc + pix] = ah / (1.f + __expf(-ah));
        cat[((size_t)b * CATc + 1 * Ec + o) * Lc + pix] = av / (1.f + __expf(-av));
        cat[((size_t)b * CATc + 2 * Ec + o) * Lc + pix] = a1 / (1.f + __expf(-a1));
        cat[((size_t)b * CATc + 3 * Ec + o) * Lc + pix] = a2 / (1.f + __expf(-a2));
    }
}

// ---------------- fuse split-K: 8 K-chunks x 12 o-groups of 8 (max TLP) ----------------
__global__ __launch_bounds__(256) void fuse_part(
    const float* __restrict__ cat, const float* __restrict__ fw,
    float* __restrict__ pxconv) {
    int l = blockIdx.x * 256 + threadIdx.x;
    int o0 = blockIdx.y * 8;
    int cs = blockIdx.z >> 1, b = blockIdx.z & 1;
    int c0 = cs * 96;
    float acc[8];
#pragma unroll
    for (int j = 0; j < 8; j++) acc[j] = 0.f;
#pragma unroll 4
    for (int c = c0; c < c0 + 96; c += 2) {
        float v0 = cat[((size_t)b * CATc + c) * Lc + l];
        float v1 = cat[((size_t)b * CATc + c + 1) * Lc + l];
#pragma unroll
        for (int j = 0; j < 8; j++) {
            acc[j] += v0 * fw[(o0 + j) * CATc + c] + v1 * fw[(o0 + j) * CATc + c + 1];
        }
    }
#pragma unroll
    for (int j = 0; j < 8; j++)
        pxconv[(((size_t)cs * Bc + b) * Cc + o0 + j) * Lc + l] = acc[j];
}

__global__ __launch_bounds__(256) void fuse_reduce(
    const float* __restrict__ pxconv, float* __restrict__ xconv) {
    size_t idx = ((size_t)blockIdx.x * 256 + threadIdx.x) * 4;   // float4 over Bc*Cc*Lc
    const size_t stride = (size_t)Bc * Cc * Lc;
    float4 s = *(const float4*)(pxconv + idx);
#pragma unroll
    for (int k = 1; k < 8; k++) {
        float4 v = *(const float4*)(pxconv + idx + (size_t)k * stride);
        s.x += v.x; s.y += v.y; s.z += v.z; s.w += v.w;
    }
    *(float4*)(xconv + idx) = s;
}

// ---------------- in_proj: xp/zp [B,L,192], o-groups of 8 for TLP ----------------
__global__ __launch_bounds__(256) void inproj_kernel(
    const float* __restrict__ xconv, const float* __restrict__ w,
    float* __restrict__ xp, float* __restrict__ zp) {
    int l = blockIdx.x * 256 + threadIdx.x;
    int o0 = blockIdx.y * 8;
    int b = blockIdx.z;
    float acc[8];
#pragma unroll
    for (int j = 0; j < 8; j++) acc[j] = 0.f;
#pragma unroll 4
    for (int c = 0; c < Cc; c += 2) {
        float v0 = xconv[((size_t)b * Cc + c) * Lc + l];
        float v1 = xconv[((size_t)b * Cc + c + 1) * Lc + l];
#pragma unroll
        for (int j = 0; j < 8; j++) {
            acc[j] += v0 * w[(o0 + j) * Cc + c] + v1 * w[(o0 + j) * Cc + c + 1];
        }
    }
#pragma unroll
    for (int j = 0; j < 8; j++) {
        int o = o0 + j;
        if (o < Ec) xp[((size_t)b * Lc + l) * Ec + o] = acc[j];
        else        zp[((size_t)b * Lc + l) * Ec + (o - Ec)] = acc[j];
    }
}

// ---------------- xdbl GEMM + fused delta softplus ----------------
__global__ __launch_bounds__(256) void xdbl_kernel(
    const float* __restrict__ xp, const float* __restrict__ xw,
    const float* __restrict__ dtw, const float* __restrict__ dtb,
    float* __restrict__ delta, float* __restrict__ Bst, float* __restrict__ Cst) {
    int rb = blockIdx.x;                 // 256 blocks, 32 rows each
    __shared__ float S[32][193];         // pad 193: conflict-free
    __shared__ float dt6s[32][6];
    const float* src = xp + (size_t)rb * 32 * Ec;
    for (int idx = threadIdx.x; idx < 32 * Ec / 4; idx += 256) {
        int fl = idx * 4;
        int r = fl / Ec, c = fl % Ec;
        float4 v = *(const float4*)(src + fl);
        S[r][c] = v.x; S[r][c + 1] = v.y; S[r][c + 2] = v.z; S[r][c + 3] = v.w;
    }
    __syncthreads();
    for (int t = threadIdx.x; t < 32 * XJ; t += 256) {
        int r = t / XJ, j = t % XJ;
        const float* wrow = xw + j * Ec;
        float s = 0.f;
#pragma unroll 4
        for (int c = 0; c < Ec; c++) s += S[r][c] * wrow[c];
        int row = rb * 32 + r;
        if (j < 6)       dt6s[r][j] = s;
        else if (j < 22) Bst[row * Nc + (j - 6)] = s;
        else             Cst[row * Nc + (j - 22)] = s;
    }
    __syncthreads();
    // delta: softplus(dt6 @ dtw^T + 2*dtb) for 32 rows x 192 e
    for (int idx = threadIdx.x; idx < 32 * Ec; idx += 256) {
        int r = idx / Ec, e = idx % Ec;
        const float* w = dtw + e * 6;
        float s = 2.f * dtb[e];
#pragma unroll
        for (int rr = 0; rr < 6; rr++) s += dt6s[r][rr] * w[rr];
        delta[(size_t)(rb * 32 + r) * Ec + e] = (s > 20.f) ? s : log1pf(__expf(s));
    }
}

// ============ chunked selective scan, thread-owns-e layout ============
// hend layout: [d][b][chunk][n][e]  (chunk stride 3072, n stride 192)
// Pend layout: [b][chunk][n][e]

__global__ __launch_bounds__(192) void scan_part1(
    const float* __restrict__ xp, const int* __restrict__ ord,
    const float* __restrict__ delta, const float* __restrict__ Bst,
    const float* __restrict__ A_log, const float* __restrict__ dirB,
    float* __restrict__ hend, float* __restrict__ Pend) {
    int chunk = blockIdx.x, b = blockIdx.y, d = blockIdx.z;
    int e = threadIdx.x;                 // 0..191
    __shared__ int lord[CHUNK];
    if (threadIdx.x < CHUNK) lord[threadIdx.x] = ord[d * Lc + chunk * CHUNK + threadIdx.x];
    __syncthreads();
    float Aen[Nc], h[Nc], P[Nc], Bd[Nc];
#pragma unroll
    for (int n = 0; n < Nc; n++) {
        Aen[n] = -__expf(A_log[e * Nc + n]);
        Bd[n] = dirB[d * Nc + n];        // block-uniform -> scalar
        h[n] = 0.f; P[n] = 1.f;
    }
    const float* dl  = delta + (size_t)b * Lc * Ec;
    const float* xpb = xp + (size_t)b * Lc * Ec;
    const float* Bb  = Bst + (size_t)b * Lc * Nc;
    int l0 = chunk * CHUNK;
#pragma unroll 2
    for (int t = 0; t < CHUNK; t++) {
        int l = l0 + t;
        float de = dl[(size_t)l * Ec + e];                 // coalesced
        float uu = xpb[(size_t)lord[t] * Ec + e];          // coalesced (uniform row)
        float dub = de * uu;
        const float* Brow = Bb + (size_t)l * Nc;           // uniform -> scalar loads
#pragma unroll
        for (int n = 0; n < Nc; n++) {
            float dA = __expf(de * Aen[n]);
            h[n] = dA * h[n] + dub * (Brow[n] + Bd[n]);
            P[n] *= dA;
        }
    }
    size_t base = ((size_t)(d * Bc + b) * NCH + chunk) * 3072 + e;
#pragma unroll
    for (int n = 0; n < Nc; n++) hend[base + n * Ec] = h[n];
    if (d == 0) {
        size_t pb = ((size_t)b * NCH + chunk) * 3072 + e;
#pragma unroll
        for (int n = 0; n < Nc; n++) Pend[pb + n * Ec] = P[n];
    }
}

__global__ __launch_bounds__(256) void scan_mid(
    float* __restrict__ hend, const float* __restrict__ Pend) {
    int blk = blockIdx.x;            // (d*2+b)*12 + sub
    int sub = blk % 12, db = blk / 12;
    int b = db & 1;
    int pair = sub * 256 + threadIdx.x;   // 0..3071 = (n,e) flat
    size_t base  = (size_t)db * NCH * 3072 + pair;
    size_t pbase = (size_t)b * NCH * 3072 + pair;
    float h = 0.f;
    for (int c = 0; c < NCH; c++) {
        float hc = hend[base + (size_t)c * 3072];
        float P  = Pend[pbase + (size_t)c * 3072];
        hend[base + (size_t)c * 3072] = h;   // h_in for chunk c
        h = P * h + hc;
    }
}

__global__ __launch_bounds__(192) void scan_part2(
    const float* __restrict__ xp, const int* __restrict__ ord,
    const float* __restrict__ delta, const float* __restrict__ Bst,
    const float* __restrict__ Cst, const float* __restrict__ A_log,
    const float* __restrict__ Dp, const float* __restrict__ dirB,
    const float* __restrict__ hend, float* __restrict__ ydir) {
    int chunk = blockIdx.x, b = blockIdx.y, d = blockIdx.z;
    int e = threadIdx.x;                 // 0..191
    __shared__ int lord[CHUNK];
    if (threadIdx.x < CHUNK) lord[threadIdx.x] = ord[d * Lc + chunk * CHUNK + threadIdx.x];
    __syncthreads();
    float Aen[Nc], h[Nc], Bd[Nc];
    size_t base = ((size_t)(d * Bc + b) * NCH + chunk) * 3072 + e;
#pragma unroll
    for (int n = 0; n < Nc; n++) {
        Aen[n] = -__expf(A_log[e * Nc + n]);
        Bd[n] = dirB[d * Nc + n];
        h[n] = hend[base + n * Ec];
    }
    float De = Dp[e];
    const float* dl  = delta + (size_t)b * Lc * Ec;
    const float* xpb = xp + (size_t)b * Lc * Ec;
    const float* Bb  = Bst + (size_t)b * Lc * Nc;
    const float* Cb  = Cst + (size_t)b * Lc * Nc;
    float* yo = ydir + ((size_t)(d * Bc + b) * Lc) * Ec + e;
    int l0 = chunk * CHUNK;
#pragma unroll 2
    for (int t = 0; t < CHUNK; t++) {
        int l = l0 + t;
        float de = dl[(size_t)l * Ec + e];
        float uu = xpb[(size_t)lord[t] * Ec + e];
        float dub = de * uu;
        const float* Brow = Bb + (size_t)l * Nc;
        const float* Crow = Cb + (size_t)l * Nc;
        float acc = De * uu;
#pragma unroll
        for (int n = 0; n < Nc; n++) {
            float dA = __expf(de * Aen[n]);
            h[n] = dA * h[n] + dub * (Brow[n] + Bd[n]);
            acc += h[n] * Crow[n];
        }
        yo[(size_t)l * Ec] = acc;                           // coalesced
    }
}

// ---------------- local cluster: one block per 8x8 tile ----------------
__global__ __launch_bounds__(64) void cluster_kernel(
    const float* __restrict__ xconv,
    const float* __restrict__ fwp, const float* __restrict__ fbp,
    const float* __restrict__ vwp, const float* __restrict__ vbp,
    const float* __restrict__ pwp, const float* __restrict__ pbp,
    const float* __restrict__ alphap, const float* __restrict__ betap,
    float* __restrict__ c96) {
    int g = blockIdx.x;
    int b = g >> 6, Wg = (g >> 3) & 7, Hg = g & 7;
    int p = threadIdx.x;
    int wi = p >> 3, hj = p & 7;
    int lsp = (Wg * 8 + wi) * 64 + (Hg * 8 + hj);
    __shared__ float fS[64][6], vS[64][6];
    __shared__ float cen[25][6], vc[25][6], cnorm[25];
    __shared__ float simb[64];
    __shared__ int kb[64];
    __shared__ float agg[25][6];
    float fr[6], vr[6];
#pragma unroll
    for (int oc = 0; oc < 6; oc++) { fr[oc] = fbp[oc]; vr[oc] = vbp[oc]; }
    for (int c = 0; c < 48; c++) {
        float v1 = xconv[((size_t)b * Cc + c) * Lc + lsp];
        float v2 = xconv[((size_t)b * Cc + 48 + c) * Lc + lsp];
#pragma unroll
        for (int oc = 0; oc < 6; oc++) {
            fr[oc] += v1 * fwp[oc * 48 + c];
            vr[oc] += v2 * vwp[oc * 48 + c];
        }
    }
#pragma unroll
    for (int oc = 0; oc < 6; oc++) { fS[p][oc] = fr[oc]; vS[p][oc] = vr[oc]; }
    __syncthreads();
    // adaptive-pool bins for 8->5
    const int bs[5] = {0, 1, 3, 4, 6}, be[5] = {2, 4, 5, 7, 8};
    for (int t = p; t < 150; t += 64) {
        int k = t / 6, oc = t % 6;
        int ki = k / 5, kj = k % 5;
        float sf = 0.f, sv = 0.f;
        int cnt = 0;
        for (int ii = bs[ki]; ii < be[ki]; ii++)
            for (int jj = bs[kj]; jj < be[kj]; jj++) {
                sf += fS[ii * 8 + jj][oc];
                sv += vS[ii * 8 + jj][oc];
                cnt++;
            }
        cen[k][oc] = sf / cnt;
        vc[k][oc] = sv / cnt;
    }
    __syncthreads();
    if (p < 25) {
        float s = 0.f;
#pragma unroll
        for (int oc = 0; oc < 6; oc++) s += cen[p][oc] * cen[p][oc];
        cnorm[p] = 1.f / fmaxf(sqrtf(s), 1e-12f);
    }
    __syncthreads();
    float fn2 = 0.f;
#pragma unroll
    for (int oc = 0; oc < 6; oc++) fn2 += fr[oc] * fr[oc];
    float finv = 1.f / fmaxf(sqrtf(fn2), 1e-12f);
    float alpha = alphap[0], beta = betap[0];
    float best = -1.f;
    int bestk = 0;
    for (int k = 0; k < 25; k++) {
        float dot = 0.f;
#pragma unroll
        for (int oc = 0; oc < 6; oc++) dot += cen[k][oc] * fr[oc];
        float xv = beta + alpha * dot * cnorm[k] * finv;
        float s = 1.f / (1.f + __expf(-xv));
        if (s > best) { best = s; bestk = k; }   // first-occurrence argmax
    }
    simb[p] = best;
    kb[p] = bestk;
    __syncthreads();
    if (p < 25) {
        float sum_s = 0.f;
        float av[6];
#pragma unroll
        for (int oc = 0; oc < 6; oc++) av[oc] = vc[p][oc];
        for (int q = 0; q < 64; q++) {
            if (kb[q] == p) {
                float s = simb[q];
                sum_s += s;
#pragma unroll
                for (int oc = 0; oc < 6; oc++) av[oc] += s * vS[q][oc];
            }
        }
        float invd = 1.f / (sum_s + 1.f);
#pragma unroll
        for (int oc = 0; oc < 6; oc++) agg[p][oc] = av[oc] * invd;
    }
    __syncthreads();
    float outp[6];
#pragma unroll
    for (int oc = 0; oc < 6; oc++) outp[oc] = agg[kb[p]][oc] * simb[p];
    float* orow = c96 + ((size_t)b * Lc + lsp) * Cc;
    for (int oo = 0; oo < Cc; oo++) {
        float s = pbp[oo];
#pragma unroll
        for (int oc = 0; oc < 6; oc++) s += outp[oc] * pwp[oo * 6 + oc];
        orow[oo] = s;
    }
}

// ---------------- cluster projection 96 -> 192, o-groups of 8 ----------------
__global__ __launch_bounds__(256) void clproj_kernel(
    const float* __restrict__ c96, const float* __restrict__ w,
    const float* __restrict__ bias, float* __restrict__ cl) {
    int l = blockIdx.x * 256 + threadIdx.x;
    int o0 = blockIdx.y * 8;
    int b = blockIdx.z;
    const float* row = c96 + ((size_t)b * Lc + l) * Cc;
    float acc[8];
#pragma unroll
    for (int j = 0; j < 8; j++) acc[j] = bias[o0 + j];
#pragma unroll 4
    for (int c = 0; c < Cc; c += 2) {
        float v0 = row[c], v1 = row[c + 1];
#pragma unroll
        for (int j = 0; j < 8; j++) {
            acc[j] += v0 * w[(o0 + j) * Cc + c] + v1 * w[(o0 + j) * Cc + c + 1];
        }
    }
#pragma unroll
    for (int j = 0; j < 8; j++)
        cl[((size_t)b * Lc + l) * Ec + o0 + j] = acc[j];
}

// ---------------- gather y dirs + 3x LayerNorm + branch softmax + out_proj ----------------
__global__ __launch_bounds__(256) void final_kernel(
    const float* __restrict__ ydir, const float* __restrict__ zp,
    const float* __restrict__ cl, const float* __restrict__ bc,
    const float* __restrict__ lnw, const float* __restrict__ lnb,
    const float* __restrict__ woutT, float* __restrict__ out) {
    __shared__ float comb[4][Ec];
    int wave = threadIdx.x >> 6, lane = threadIdx.x & 63;
    int row = blockIdx.x * 4 + wave;
    int b = row >> 12, lp = row & (Lc - 1);
    int iv0 = inv_d0(lp), iv1 = inv_d1(lp), iv2 = inv_d2(lp), iv3 = inv_d3(lp);
    const float* y0 = ydir + ((size_t)(0 * Bc + b) * Lc + iv0) * Ec;
    const float* y1 = ydir + ((size_t)(1 * Bc + b) * Lc + iv1) * Ec;
    const float* y2 = ydir + ((size_t)(2 * Bc + b) * Lc + iv2) * Ec;
    const float* y3 = ydir + ((size_t)(3 * Bc + b) * Lc + iv3) * Ec;
    const float* zr = zp + ((size_t)b * Lc + lp) * Ec;
    const float* cr = cl + ((size_t)b * Lc + lp) * Ec;
    float ys[3], zv[3], cv[3];
    float s1 = 0, s2 = 0, z1 = 0, z2 = 0, c1 = 0, c2 = 0;
#pragma unroll
    for (int t = 0; t < 3; t++) {
        int i = lane + t * 64;
        float v = y0[i] + y1[i] + y2[i] + y3[i];
        ys[t] = v; s1 += v; s2 += v * v;
        float z = zr[i]; zv[t] = z; z1 += z; z2 += z * z;
        float c = cr[i]; cv[t] = c; c1 += c; c2 += c * c;
    }
#pragma unroll
    for (int o = 32; o >= 1; o >>= 1) {
        s1 += __shfl_xor(s1, o, 64); s2 += __shfl_xor(s2, o, 64);
        z1 += __shfl_xor(z1, o, 64); z2 += __shfl_xor(z2, o, 64);
        c1 += __shfl_xor(c1, o, 64); c2 += __shfl_xor(c2, o, 64);
    }
    const float invE = 1.f / (float)Ec;
    float ym = s1 * invE, yvr = rsqrtf(s2 * invE - ym * ym + 1e-5f);
    float zm = z1 * invE, zvr = rsqrtf(z2 * invE - zm * zm + 1e-5f);
    float cm = c1 * invE, cvr = rsqrtf(c2 * invE - cm * cm + 1e-5f);
#pragma unroll
    for (int t = 0; t < 3; t++) {
        int i = lane + t * 64;
        float g = lnw[i], bb = lnb[i];
        float a0 = (ys[t] - ym) * yvr * g + bb;
        float a1 = (zv[t] - zm) * zvr * g + bb;
        float a2 = (cv[t] - cm) * cvr * g + bb;
        float w0 = bc[i], w1 = bc[Ec + i], w2 = bc[2 * Ec + i];
        float mx = fmaxf(w0, fmaxf(w1, w2));
        float e0 = __expf(w0 - mx), e1 = __expf(w1 - mx), e2 = __expf(w2 - mx);
        float inv = 1.f / (e0 + e1 + e2);
        comb[wave][i] = (e0 * a0 + e1 * a1 + e2 * a2) * inv;
    }
    __syncthreads();
    // out_proj: lane = o; woutT[k][o] coalesced; comb[wave][k] LDS broadcast.
    float r0 = 0.f, r1 = 0.f;
#pragma unroll 4
    for (int k = 0; k < Ec; k++) {
        float cvk = comb[wave][k];
        float w0 = woutT[k * Cc + lane];
        float w1 = woutT[k * Cc + 64 + lane];
        r0 += cvk * w0;
        r1 += cvk * w1;
    }
    float* orow = out + (size_t)row * Cc;
    orow[lane] = r0;                      // o = 0..63, coalesced
    if (lane < 32) orow[64 + lane] = r1;  // o = 64..95, coalesced
}

extern "C" void kernel_launch(void* const* d_in, const int* in_sizes, int n_in,
                              void* d_out, int out_size, void* d_ws, size_t ws_size,
                              hipStream_t stream) {
    const float* x       = (const float*)d_in[0];
    const float* wh      = (const float*)d_in[3];
    const float* wv      = (const float*)d_in[4];
    const float* wd1     = (const float*)d_in[5];
    const float* wd2     = (const float*)d_in[6];
    const float* fw      = (const float*)d_in[7];
    const float* ipw     = (const float*)d_in[8];
    const float* xw      = (const float*)d_in[9];
    const float* dtw     = (const float*)d_in[10];
    const float* dtb     = (const float*)d_in[11];
    const float* A_log   = (const float*)d_in[12];
    const float* Dp      = (const float*)d_in[13];
    const float* dirB    = (const float*)d_in[14];
    const float* wout    = (const float*)d_in[15];
    const float* alphap  = (const float*)d_in[16];
    const float* betap   = (const float*)d_in[17];
    const float* fwp     = (const float*)d_in[18];
    const float* fbp     = (const float*)d_in[19];
    const float* vwp     = (const float*)d_in[20];
    const float* vbp     = (const float*)d_in[21];
    const float* pwp     = (const float*)d_in[22];
    const float* pbp     = (const float*)d_in[23];
    const float* clw     = (const float*)d_in[24];
    const float* clb     = (const float*)d_in[25];
    const float* bc      = (const float*)d_in[26];
    const float* lnw     = (const float*)d_in[27];
    const float* lnb     = (const float*)d_in[28];
    float* out = (float*)d_out;

    float* wsf = (float*)d_ws;
    size_t off = 0;
    int* ord      = (int*)wsf;             off += 4 * Lc;                 // 64 KB
    float* cat    = wsf + off;             off += (size_t)Bc * CATc * Lc; // 24 MB (reused as ydir)
    float* xconv  = wsf + off;             off += (size_t)Bc * Cc * Lc;   // 3 MB
    float* xp     = wsf + off;             off += (size_t)Bc * Lc * Ec;   // 6 MB (reused as c96)
    float* zpb    = wsf + off;             off += (size_t)Bc * Lc * Ec;   // 6 MB
    float* deltab = wsf + off;             off += (size_t)Bc * Lc * Ec;   // 6 MB (reused as cl)
    float* Bst    = wsf + off;             off += (size_t)Bc * Lc * Nc;   // 0.5 MB
    float* Cst    = wsf + off;             off += (size_t)Bc * Lc * Nc;   // 0.5 MB
    float* hend   = wsf + off;             off += (size_t)4 * Bc * NCH * Ec * Nc; // 25.2 MB
    float* Pend   = wsf + off;             off += (size_t)Bc * NCH * Ec * Nc;     // 6.3 MB
    float* woutT  = wsf + off;             off += (size_t)Ec * Cc + 64;           // 74 KB (+64 pad)
    // total ≈ 79.9 MB
    float* ydir = cat;     // cat dead after fuse; same size as ydir
    float* c96  = xp;      // xp dead after scan_part2 (stream-serialized)
    float* cl   = deltab;  // delta dead after scan_part2
    // fuse 8-way split-K partials: 8*Bc*Cc*Lc = 6,291,456 floats — spans
    // xp..hend-prefix (xp/zpb/delta/Bst/Cst written only after fuse_reduce;
    // all stream-serialized)
    float* pxconv = xp;

    setup_kernel<<<88, 256, 0, stream>>>(ord, wout, woutT);
    conv_kernel<<<dim3(16, 96, 2), 256, 0, stream>>>(x, wh, wv, wd1, wd2, cat);
    fuse_part<<<dim3(16, 12, 16), 256, 0, stream>>>(cat, fw, pxconv);
    fuse_reduce<<<768, 256, 0, stream>>>(pxconv, xconv);
    inproj_kernel<<<dim3(16, 48, 2), 256, 0, stream>>>(xconv, ipw, xp, zpb);
    xdbl_kernel<<<256, 256, 0, stream>>>(xp, xw, dtw, dtb, deltab, Bst, Cst);
    scan_part1<<<dim3(NCH, 2, 4), 192, 0, stream>>>(xp, ord, deltab, Bst,
                                                    A_log, dirB, hend, Pend);
    scan_mid<<<96, 256, 0, stream>>>(hend, Pend);
    scan_part2<<<dim3(NCH, 2, 4), 192, 0, stream>>>(xp, ord, deltab, Bst, Cst,
                                                    A_log, Dp, dirB, hend, ydir);
    cluster_kernel<<<128, 64, 0, stream>>>(xconv, fwp, fbp, vwp, vbp, pwp, pbp,
                                           alphap, betap, c96);
    clproj_kernel<<<dim3(16, 24, 2), 256, 0, stream>>>(c96, clw, clb, cl);
    final_kernel<<<2048, 256, 0, stream>>>(ydir, zpb, cl, bc, lnw, lnb, woutT, out);
}